// Round 6
// baseline (370.980 us; speedup 1.0000x reference)
//
#include <hip/hip_runtime.h>
#include <hip/hip_bf16.h>
#include <math.h>

typedef __hip_bfloat16 bf16;
typedef __attribute__((ext_vector_type(8))) short bf16x8v;   // 8 bf16 MFMA operand
typedef __attribute__((ext_vector_type(4))) float f32x4;     // MFMA accumulator

// HGT layer, round 19 = round 18 + isolated XCD swizzle on gemm3s + merged ugemm pair.
// R18 STATE: gemm3s 115.5us @ 1.02 PF effective, FETCH 193MB vs ~53MB compulsory ->
//   ~140MB A-tile refetch because consecutive bids round-robin across XCDs (10 column
//   blocks sharing an A row-tile land on 8 different L2s). Fix: bijective XCD-chunked
//   swizzle (R17's, now ISOLATED - scatter stays LAST, not first).
// ugemm merge: ugemm_a writes out[0..NA) over d_out bytes where AGb lived -> edge now
//   writes AGb to a dedicated ws buffer (Qb3 stays in d_out as the Q input). Then both
//   ugemm_ln dispatches merge into ONE 548-block dispatch (tail-fill, one less gap).
// EDGE KERNEL AT ROOFLINE (R14-R16): replay(L3-hot)=cold ~109us; ~640MB gather/109us ~=
//   6 TB/s fabric ceiling. Untouched.
// Dispatches: [zero] [conv||fold6||hist3] [comb5||alloc3b] [gemm3-swz + scatter-last]
//             [edge] [ugemm a+b merged]
// Kept: int2 meta {start,cnt}; int2 CSR lists {src, ML-t}; b-blocks-first edge;
//   shfl_xor(ex,32); VGPR<=64 rule for edge (R15: 72 VGPR = occupancy cliff);
//   scatter-last (R17: scatter-first = whole-GPU atomic phase before gemm, +14us).
//   fold6:    Wq1x/Wq2x/Wq3x = blockdiag(Watt_e*prior/sqrt32)@Wq ; Wmx = blockdiagT(Wmsg)@Wm
//   combine5: RTE-table weights, panel-paired for interleaved outputs
//   gemm3:    seg0 rte->(RKM1,RKM2,RM3p); seg1 Ha->(Qa1,Qa2,KMa1,Ma3); seg2 Hb->(Qb3,KMb)
//   edge:     wave=node, ONE pass/edge-type (softmax by linearity), 4-grouped row loads.
//   ugemm_ln: x=AG@Wa^T -> u=a*x+(1-a)*H_bf -> LN -> fp32 out.
// alloc3b: atomic target must be wave-uniform (R7 lesson: divergent slot = 120k serial atomics).

__device__ __forceinline__ float eluf(float x) { return x > 0.f ? x : (__expf(x) - 1.f); }
__device__ __forceinline__ float b2f(unsigned short u) { return __uint_as_float((unsigned)u << 16); }
__device__ __forceinline__ unsigned short f2b(float f) {
    unsigned u = __float_as_uint(f);
    return (unsigned short)((u + 0x7fffu + ((u >> 16) & 1u)) >> 16);
}
__device__ __forceinline__ void unpack8(uint4 u, float* o) {
    o[0] = __uint_as_float(u.x << 16); o[1] = __uint_as_float(u.x & 0xffff0000u);
    o[2] = __uint_as_float(u.y << 16); o[3] = __uint_as_float(u.y & 0xffff0000u);
    o[4] = __uint_as_float(u.z << 16); o[5] = __uint_as_float(u.z & 0xffff0000u);
    o[6] = __uint_as_float(u.w << 16); o[7] = __uint_as_float(u.w & 0xffff0000u);
}
__device__ __forceinline__ void unpack4(ushort4 u, float* o) {
    o[0] = b2f(u.x); o[1] = b2f(u.y); o[2] = b2f(u.z); o[3] = b2f(u.w);
}

#define ASYNC_LDS16(g, l) \
    __builtin_amdgcn_global_load_lds((const __attribute__((address_space(1))) void*)(g), \
                                     (__attribute__((address_space(3))) void*)(l), 16, 0, 0)

// ---- tiny zero dispatch (must precede hist3's atomics; cannot share its dispatch) ----
__global__ void zero_kernel(int* __restrict__ z0, int nz0, int* __restrict__ z1, int nz1)
{
    for (int i = blockIdx.x * 256 + threadIdx.x; i < nz0; i += gridDim.x * 256) z0[i] = 0;
    if (blockIdx.x == 0 && threadIdx.x < (unsigned)nz1) z1[threadIdx.x] = 0;
}

// ---- merged: 6 fp32->bf16 converts (blocks 0..3071) || fold6 (3072..4607) || hist3 (rest) ----
__global__ void conv_fold_hist_kernel(
    const float* s0, bf16* o0, int n0, const float* s1, bf16* o1, int n1,
    const float* s2, bf16* o2, int n2, const float* s3, bf16* o3, int n3,
    const float* s4, bf16* o4, int n4, const float* s5, bf16* o5, int n5,
    const float* __restrict__ Watt, const float* __restrict__ Wmsg,
    const float* __restrict__ prior,
    const float* __restrict__ Wq, const float* __restrict__ Wm,
    bf16* __restrict__ WcatA, bf16* __restrict__ WcatB,
    float* __restrict__ Wmx1f, float* __restrict__ Wmx2f, float* __restrict__ Wmx3f,
    const int* __restrict__ d1, const int* __restrict__ d2, const int* __restrict__ d3,
    int2* __restrict__ m1, int2* __restrict__ m2, int2* __restrict__ m3,
    int E1, int E2, int E3)
{
    const int bid = blockIdx.x;
    if (bid < 3072) {
        // converts: 512 blocks per segment, grid-stride
        const int seg = bid >> 9;
        const int lb = bid & 511;
        const float* sp; bf16* op; int n8;
        switch (seg) {
            case 0: sp = s0; op = o0; n8 = n0; break;
            case 1: sp = s1; op = o1; n8 = n1; break;
            case 2: sp = s2; op = o2; n8 = n2; break;
            case 3: sp = s3; op = o3; n8 = n3; break;
            case 4: sp = s4; op = o4; n8 = n4; break;
            default: sp = s5; op = o5; n8 = n5; break;
        }
        for (int i = lb * 256 + threadIdx.x; i < n8; i += 512 * 256) {
            const float4* p = (const float4*)(sp + (size_t)i * 8);
            float4 a = p[0], b = p[1];
            uint4 u;
            u.x = (unsigned)f2b(a.x) | ((unsigned)f2b(a.y) << 16);
            u.y = (unsigned)f2b(a.z) | ((unsigned)f2b(a.w) << 16);
            u.z = (unsigned)f2b(b.x) | ((unsigned)f2b(b.y) << 16);
            u.w = (unsigned)f2b(b.z) | ((unsigned)f2b(b.w) << 16);
            *(uint4*)(op + (size_t)i * 8) = u;
        }
        return;
    }
    if (bid >= 4608) {
        // hist3 (last: fills conv's tail). Needs meta zeroed (zero dispatch).
        int i = (bid - 4608) * 256 + threadIdx.x;
        if (i < E1) atomicAdd(&m1[d1[i]].y, 1);
        else if (i < E1 + E2) atomicAdd(&m2[d2[i - E1]].y, 1);
        else if (i < E1 + E2 + E3) atomicAdd(&m3[d3[i - E1 - E2]].y, 1);
        return;
    }
    // fold6
    const int fb = bid - 3072;
    const int g = fb >> 8;
    const int i = fb & 255;
    const int j = threadIdx.x;
    const int h = i >> 5, r = i & 31;
    const float* A; const float* W; float sc = 1.f; int tr = 0;
    bf16* ob; float* of = nullptr;
    const float isq = 0.17677669529663687f;
    switch (g) {
        case 0: A = Watt;        sc = prior[0] * isq; W = Wq;         ob = WcatA;                       break;
        case 1: A = Watt + 1024; sc = prior[1] * isq; W = Wq;         ob = WcatA + (size_t)256 * 256;   break;
        case 2: A = Watt + 2048; sc = prior[2] * isq; W = Wq + 65536; ob = WcatB;                       break;
        case 3: A = Wmsg;        tr = 1; W = Wm;         ob = WcatA + (size_t)768 * 256;  of = Wmx1f;   break;
        case 4: A = Wmsg + 1024; tr = 1; W = Wm + 65536; ob = WcatB + (size_t)512 * 256;  of = Wmx2f;   break;
        default:A = Wmsg + 2048; tr = 1; W = Wm;         ob = WcatA + (size_t)1024 * 256; of = Wmx3f;   break;
    }
    __shared__ float arow[32];
    if (j < 32) arow[j] = (tr ? A[j * 32 + r] : A[r * 32 + j]) * sc;
    __syncthreads();
    float acc = 0.f;
    for (int k = 0; k < 32; ++k) acc += arow[k] * W[(size_t)(h * 32 + k) * 256 + j];
    ((unsigned short*)ob)[(size_t)i * 256 + j] = f2b(acc);
    if (of) of[(size_t)i * 256 + j] = acc;
}

// ---- merged: 5 RTE-weight combines (blocks 0..1279) || alloc3b (rest) ----
__global__ void comb5alloc_kernel(const float* __restrict__ Wk,
                                  const float* __restrict__ Wmx1f, const float* __restrict__ Wmx2f,
                                  const float* __restrict__ Wmx3f,
                                  const float* __restrict__ rteW, const float* __restrict__ rteb,
                                  bf16* __restrict__ WcatR, float* __restrict__ bcatR,
                                  int2* __restrict__ meta, int* __restrict__ cursor,
                                  int* __restrict__ gtot, int NA, int NB, int bps)
{
    if (blockIdx.x >= 1280) {
        // alloc3b: needs meta.y (prev dispatch) + gtot zeroed
        const int lid = (int)blockIdx.x - 1280;
        const int slot = lid / bps;
        const int base = (slot == 0) ? 0 : (slot == 1) ? NA : 2 * NA;
        const int len = (slot == 2) ? NB : NA;
        int i = (lid % bps) * 256 + threadIdx.x;
        if (i >= len) return;
        int* gp = gtot + slot;         // uniform across the block -> wave-reduced atomics
        int idx = base + i;
        int s = atomicAdd(gp, meta[idx].y);
        meta[idx].x = s; cursor[idx] = s;
        return;
    }
    const int g = blockIdx.x >> 8;
    const int i = blockIdx.x & 255;
    const int j = threadIdx.x;
    const float* Wp; const float* rW; const float* rb; int op;
    switch (g) {
        case 0: Wp = Wk;         rW = rteW;         rb = rteb;       op = 0; break;
        case 1: Wp = Wk + 65536; rW = rteW + 65536; rb = rteb + 256; op = 2; break;
        case 2: Wp = Wmx1f;      rW = rteW;         rb = rteb;       op = 1; break;
        case 3: Wp = Wmx2f;      rW = rteW + 65536; rb = rteb + 256; op = 3; break;
        default:Wp = Wmx3f;      rW = rteW;         rb = rteb;       op = 4; break;
    }
    __shared__ float wrow[256];
    wrow[j] = Wp[i * 256 + j];
    __syncthreads();
    float acc = 0.f;
    for (int k = 0; k < 256; ++k) acc += wrow[k] * rW[k * 256 + j];
    ((unsigned short*)WcatR)[(size_t)(op * 256 + i) * 256 + j] = f2b(acc);
    if (j == 0) {
        float b = 0.f;
        for (int k = 0; k < 256; ++k) b += wrow[k] * rb[k];
        bcatR[op * 256 + i] = b;
    }
}

// ---- shared MFMA GEMM body: C{0..4} = A@Wcat^T (+bcat); stride-masked outputs ----
__device__ __forceinline__ void gemm_body(
    const bf16* __restrict__ A, const bf16* __restrict__ Wcat,
    const float* __restrict__ bcat,
    bf16* C0, bf16* C1, bf16* C2, bf16* C3, bf16* C4,
    int wideMask, int M, int bx, int by, char* As, char* Bs)
{
    const int tid = threadIdx.x;
    const int wid = tid >> 6, lane = tid & 63;
    const size_t row0 = (size_t)bx * 128;
    const int gcol0 = by * 128;
    const int cb = by >> 1;
    const int lcol0 = (by & 1) * 128;
    bf16* Csel = (cb == 0) ? C0 : (cb == 1) ? C1 : (cb == 2) ? C2 : (cb == 3) ? C3 : C4;
    const size_t cstride = ((wideMask >> cb) & 1) ? 512 : 256;
    const int wr = wid >> 1, wc = wid & 1;

    f32x4 zero = {0.f, 0.f, 0.f, 0.f};
    f32x4 acc[4][4];
#pragma unroll
    for (int m = 0; m < 4; ++m)
#pragma unroll
        for (int n = 0; n < 4; ++n) acc[m][n] = zero;

    const int sr = wid * 32 + (lane >> 3);
    const int scc = (lane & 7) << 4;
    const char* Ab = (const char*)A;
    const char* Wb = (const char*)Wcat;

    for (int k0 = 0; k0 < 512; k0 += 128) {
#pragma unroll
        for (int i = 0; i < 4; ++i) {
            const int r = sr + i * 8;
            const int csw = scc ^ ((r & 7) << 4);
            const int ldso = wid * 4096 + i * 1024;
            ASYNC_LDS16(Ab + (row0 + r) * 512 + k0 + csw, As + ldso);
            ASYNC_LDS16(Wb + (size_t)(gcol0 + r) * 512 + k0 + csw, Bs + ldso);
        }
        __syncthreads();
#pragma unroll
        for (int kk = 0; kk < 2; ++kk) {
            bf16x8v a[4], b[4];
            const int cbase = kk * 64 + ((lane >> 4) << 4);
#pragma unroll
            for (int m = 0; m < 4; ++m) {
                const int r = wr * 64 + m * 16 + (lane & 15);
                a[m] = *(const bf16x8v*)(As + r * 128 + (cbase ^ ((r & 7) << 4)));
            }
#pragma unroll
            for (int n = 0; n < 4; ++n) {
                const int r = wc * 64 + n * 16 + (lane & 15);
                b[n] = *(const bf16x8v*)(Bs + r * 128 + (cbase ^ ((r & 7) << 4)));
            }
#pragma unroll
            for (int m = 0; m < 4; ++m)
#pragma unroll
                for (int n = 0; n < 4; ++n)
                    acc[m][n] = __builtin_amdgcn_mfma_f32_16x16x32_bf16(a[m], b[n], acc[m][n], 0, 0, 0);
        }
        __syncthreads();
    }
    const int orow = (lane >> 4) << 2;
    const int ocol = lane & 15;
    float bv[4];
#pragma unroll
    for (int n = 0; n < 4; ++n)
        bv[n] = bcat ? bcat[gcol0 + wc * 64 + n * 16 + ocol] : 0.f;
    unsigned short* Cp = (unsigned short*)Csel;
#pragma unroll
    for (int m = 0; m < 4; ++m) {
#pragma unroll
        for (int j = 0; j < 4; ++j) {
            const size_t row = row0 + wr * 64 + m * 16 + orow + j;
            if ((int)row >= M) continue;
#pragma unroll
            for (int n = 0; n < 4; ++n) {
                const int col = lcol0 + wc * 64 + n * 16 + ocol;
                Cp[row * cstride + col] = f2b(acc[m][n][j] + bv[n]);
            }
        }
    }
}

// ---- merged: 3-segment GEMM (XCD-chunked swizzle) || scatter3 LAST.
// Swizzle: consecutive XCD-local ids share the A row-tile -> A fetched into ONE L2,
// not 8 (R18 counters: 193MB FETCH vs 53MB compulsory = the refetch this kills).
// Scatter blocks fill the gemm drain tail (R17 lesson: scatter-first serializes).
__global__ __launch_bounds__(256) void gemm3s_kernel(
    const bf16* A0, const bf16* W0, const float* bc0,
    bf16* o00, bf16* o01, bf16* o02, bf16* o03, bf16* o04, int mask0, int M0,
    const bf16* A1, const bf16* W1,
    bf16* o10, bf16* o11, bf16* o12, bf16* o13, bf16* o14, int mask1, int M1,
    const bf16* A2, const bf16* W2,
    bf16* o20, bf16* o21, bf16* o22, int mask2, int M2,
    int b0, int b1, int btot,
    const int* __restrict__ d1, const int* __restrict__ d2, const int* __restrict__ d3,
    const int* __restrict__ s1, const int* __restrict__ s2, const int* __restrict__ s3,
    const int* __restrict__ tv1, const int* __restrict__ tv2, const int* __restrict__ tv3,
    int* __restrict__ cur1, int* __restrict__ cur2, int* __restrict__ cur3,
    int2* __restrict__ el1, int2* __restrict__ el2, int2* __restrict__ el3,
    int E1, int E2, int E3, int ml)
{
    __shared__ __align__(16) char As[16384];
    __shared__ __align__(16) char Bs[16384];
    const int bid = blockIdx.x;
    if (bid >= btot) {
        // scatter3: needs cursors (prev dispatch); completes before edge (dispatch boundary)
        int i = (bid - btot) * 256 + threadIdx.x;
        if (i < E1) {
            int p = atomicAdd(&cur1[d1[i]], 1);
            el1[p] = make_int2(s1[i], ml - tv1[i]);
        } else if (i < E1 + E2) {
            int e = i - E1; int p = atomicAdd(&cur2[d2[e]], 1);
            el2[p] = make_int2(s2[e], ml - tv2[e]);
        } else if (i < E1 + E2 + E3) {
            int e = i - E1 - E2; int p = atomicAdd(&cur3[d3[e]], 1);
            el3[p] = make_int2(s3[e], ml - tv3[e]);
        }
        return;
    }
    // bijective XCD-chunked remap (m204 form): xcd = bid&7 (HW round-robin), each XCD
    // walks a CONTIGUOUS lbid chunk -> same-row-tile column panels stay on one L2.
    const int q = btot >> 3, r = btot & 7;
    const int xcd = bid & 7, idx = bid >> 3;
    const int lbid = (xcd < r ? xcd * (q + 1) : r * (q + 1) + (xcd - r) * q) + idx;
    if (lbid < b0) {
        gemm_body(A0, W0, bc0, o00, o01, o02, o03, o04, mask0, M0,
                  lbid / 10, lbid % 10, As, Bs);
    } else if (lbid < b1) {
        const int lid = lbid - b0;
        gemm_body(A1, W1, nullptr, o10, o11, o12, o13, o14, mask1, M1,
                  lid / 10, lid % 10, As, Bs);
    } else {
        const int lid = lbid - b1;
        gemm_body(A2, W2, nullptr, o20, o21, o22, o22, o22, mask2, M2,
                  lid / 6, lid % 6, As, Bs);
    }
}

// ---- fused update-GEMM + LayerNorm body ----
__device__ __forceinline__ void ugemm_ln_body(
    const bf16* __restrict__ AG, const bf16* __restrict__ Wp,
    const bf16* __restrict__ Hbf, const float* __restrict__ g,
    const float* __restrict__ b, const float* __restrict__ ra,
    float* __restrict__ out, int M, int bx,
    char* As, char* Bs, float (*red)[8])
{
    const int tid = threadIdx.x;
    const int wid = tid >> 6, lane = tid & 63;
    const int wr = wid >> 2, wc = wid & 3;
    const size_t row0 = (size_t)bx * 128;

    f32x4 zero = {0.f, 0.f, 0.f, 0.f};
    f32x4 acc[4][4];
#pragma unroll
    for (int m = 0; m < 4; ++m)
#pragma unroll
        for (int n = 0; n < 4; ++n) acc[m][n] = zero;

    const char* Ab = (const char*)AG;
    const char* Wb = (const char*)Wp;
    for (int k0 = 0; k0 < 512; k0 += 128) {
#pragma unroll
        for (int i = 0; i < 2; ++i) {
            const int r = wid * 16 + i * 8 + (lane >> 3);
            const int csw = ((lane & 7) << 4) ^ ((r & 7) << 4);
            ASYNC_LDS16(Ab + (row0 + r) * 512 + k0 + csw, As + (wid * 16 + i * 8) * 128);
        }
#pragma unroll
        for (int i = 0; i < 4; ++i) {
            const int r = wid * 32 + i * 8 + (lane >> 3);
            const int csw = ((lane & 7) << 4) ^ ((r & 7) << 4);
            ASYNC_LDS16(Wb + (size_t)r * 512 + k0 + csw, Bs + (wid * 32 + i * 8) * 128);
        }
        __syncthreads();
#pragma unroll
        for (int kk = 0; kk < 2; ++kk) {
            bf16x8v a[4], bv[4];
            const int cbase = kk * 64 + ((lane >> 4) << 4);
#pragma unroll
            for (int m = 0; m < 4; ++m) {
                const int r = wr * 64 + m * 16 + (lane & 15);
                a[m] = *(const bf16x8v*)(As + r * 128 + (cbase ^ ((r & 7) << 4)));
            }
#pragma unroll
            for (int n = 0; n < 4; ++n) {
                const int r = wc * 64 + n * 16 + (lane & 15);
                bv[n] = *(const bf16x8v*)(Bs + r * 128 + (cbase ^ ((r & 7) << 4)));
            }
#pragma unroll
            for (int m = 0; m < 4; ++m)
#pragma unroll
                for (int n = 0; n < 4; ++n)
                    acc[m][n] = __builtin_amdgcn_mfma_f32_16x16x32_bf16(a[m], bv[n], acc[m][n], 0, 0, 0);
        }
        __syncthreads();
    }
    const float alpha = 1.f / (1.f + __expf(-ra[0]));
    const float beta = 1.f - alpha;
    const int orow = (lane >> 4) << 2;
    const int ocol = lane & 15;
    float gv[4], bb[4];
#pragma unroll
    for (int n = 0; n < 4; ++n) {
        gv[n] = g[wc * 64 + n * 16 + ocol];
        bb[n] = b[wc * 64 + n * 16 + ocol];
    }
    const unsigned short* Hp = (const unsigned short*)Hbf;
#pragma unroll
    for (int m = 0; m < 4; ++m) {
#pragma unroll
        for (int j = 0; j < 4; ++j) {
            const int rl = wr * 64 + m * 16 + orow + j;
            const size_t grow = row0 + rl;
            float s = 0.f, s2 = 0.f;
#pragma unroll
            for (int n = 0; n < 4; ++n) {
                const int col = wc * 64 + n * 16 + ocol;
                float hv = ((int)grow < M) ? b2f(Hp[grow * 256 + col]) : 0.f;
                float u = alpha * acc[m][n][j] + beta * hv;
                acc[m][n][j] = u;
                s += u; s2 += u * u;
            }
            s += __shfl_xor(s, 1); s2 += __shfl_xor(s2, 1);
            s += __shfl_xor(s, 2); s2 += __shfl_xor(s2, 2);
            s += __shfl_xor(s, 4); s2 += __shfl_xor(s2, 4);
            s += __shfl_xor(s, 8); s2 += __shfl_xor(s2, 8);
            if (ocol == 0) { red[rl][wc] = s; red[rl][4 + wc] = s2; }
        }
    }
    __syncthreads();
#pragma unroll
    for (int m = 0; m < 4; ++m) {
#pragma unroll
        for (int j = 0; j < 4; ++j) {
            const int rl = wr * 64 + m * 16 + orow + j;
            const size_t grow = row0 + rl;
            if ((int)grow >= M) continue;
            float S = red[rl][0] + red[rl][1] + red[rl][2] + red[rl][3];
            float S2 = red[rl][4] + red[rl][5] + red[rl][6] + red[rl][7];
            const float mu = S * 0.00390625f;
            const float var = S2 * 0.00390625f - mu * mu;
            const float inv = rsqrtf(var + 1e-5f);
#pragma unroll
            for (int n = 0; n < 4; ++n) {
                const int col = wc * 64 + n * 16 + ocol;
                out[grow * 256 + col] = (acc[m][n][j] - mu) * inv * gv[n] + bb[n];
            }
        }
    }
}

// ---- merged ugemm+LN for BOTH node types in one dispatch (a blocks first) ----
// SAFE only because AGb now lives in ws, not under ugemm_a's out[0..NA) writes.
__global__ __launch_bounds__(512) void ugemm2_ln_kernel(
    const bf16* AGa, const bf16* Wpa, const bf16* Ha_bf, const float* ga,
    const float* ba, const float* raa, float* outa, int Ma, int nba,
    const bf16* AGb, const bf16* Wpb, const bf16* Hb_bf, const float* gb,
    const float* bb, const float* rab, float* outb, int Mb)
{
    __shared__ __align__(16) char As[16384];
    __shared__ __align__(16) char Bs[32768];
    __shared__ float red[128][8];
    const int bid = blockIdx.x;
    if (bid < nba) {
        ugemm_ln_body(AGa, Wpa, Ha_bf, ga, ba, raa, outa, Ma, bid, As, Bs, red);
    } else {
        ugemm_ln_body(AGb, Wpb, Hb_bf, gb, bb, rab, outb, Mb, bid - nba, As, Bs, red);
    }
}

// ---- single-pass edge accumulate, interleaved rows (type-a edge types) ----
// 4-grouped row loads (R14 structure, VGPR-safe).
__device__ __forceinline__ void epass16(
    const bf16* __restrict__ KM, const bf16* __restrict__ RKM,
    const int2* __restrict__ el, int beg, int num,
    int sx_l, int tt_l,                      // preloaded chunk-0 indices (per-lane)
    const float q[8], int lane,
    float s[8], float& denOut)
{
    float den = 0.f;
    const char* KMb = (const char*)KM + lane * 16;
    const char* RMb = (const char*)RKM + lane * 16;
    auto edge = [&](uint4 km, uint4 rm) {
        float a[8], b[8];
        unpack8(km, a); unpack8(rm, b);
#pragma unroll
        for (int x = 0; x < 8; ++x) a[x] += b[x];
        float p = a[0] * q[0] + a[1] * q[1] + a[2] * q[2] + a[3] * q[3]
                + a[4] * q[4] + a[5] * q[5] + a[6] * q[6] + a[7] * q[7];
        p += __shfl_xor(p, 1); p += __shfl_xor(p, 2);
        float ex = __expf(p);
        float exb = __shfl_xor(ex, 32);   // lane 32+i <- lane i's reduced ex (lanes<32: unused)
        den += exb;
#pragma unroll
        for (int x = 0; x < 8; ++x) s[x] += exb * a[x];   // meaningful on M lanes only
    };
    for (int c0 = 0; c0 < num; c0 += 64) {
        int nc = num - c0; if (nc > 64) nc = 64;
        if (c0 > 0) {
            sx_l = 0; tt_l = 0;
            if (lane < nc) { int2 e = el[beg + c0 + lane]; sx_l = e.x; tt_l = e.y; }
        }
        for (int i0 = 0; i0 < nc; i0 += 4) {
            const int rem = nc - i0;
            const int a0 = __shfl(sx_l, i0),     b0 = __shfl(tt_l, i0);
            const int a1 = __shfl(sx_l, i0 | 1), b1 = __shfl(tt_l, i0 | 1);
            const int a2 = __shfl(sx_l, i0 | 2), b2 = __shfl(tt_l, i0 | 2);
            const int a3 = __shfl(sx_l, i0 | 3), b3 = __shfl(tt_l, i0 | 3);
            uint4 km0, rm0, km1, rm1, km2, rm2, km3, rm3;
            km0 = *(const uint4*)(KMb + (size_t)a0 * 1024);
            rm0 = *(const uint4*)(RMb + (size_t)b0 * 1024);
            if (rem > 1) {
                km1 = *(const uint4*)(KMb + (size_t)a1 * 1024);
                rm1 = *(const uint4*)(RMb + (size_t)b1 * 1024);
            }
            if (rem > 2) {
                km2 = *(const uint4*)(KMb + (size_t)a2 * 1024);
                rm2 = *(const uint4*)(RMb + (size_t)b2 * 1024);
            }
            if (rem > 3) {
                km3 = *(const uint4*)(KMb + (size_t)a3 * 1024);
                rm3 = *(const uint4*)(RMb + (size_t)b3 * 1024);
            }
            edge(km0, rm0);
            if (rem > 1) edge(km1, rm1);
            if (rem > 2) edge(km2, rm2);
            if (rem > 3) edge(km3, rm3);
        }
    }
    denOut = den;
}

// ---- single-pass edge accumulate, split rows (e3), 4-grouped ----
__device__ __forceinline__ void epass8(
    const bf16* __restrict__ Kh, const bf16* __restrict__ RKh,   // K halves, stride 512 el
    const bf16* __restrict__ Mt, const bf16* __restrict__ RMt,   // stride 256 el
    const int2* __restrict__ el, int beg, int num,
    int sx_l, int tt_l,
    const float q[4], int lane,
    float s[4], float& denOut)
{
    float den = 0.f;
    const char* Kb = (const char*)Kh + lane * 8;
    const char* Rb = (const char*)RKh + lane * 8;
    const char* Mb = (const char*)Mt + lane * 8;
    const char* Ub = (const char*)RMt + lane * 8;
    auto edge = [&](ushort4 kv, ushort4 rv, ushort4 mv, ushort4 uv) {
        float a[4], b[4], m[4], r[4];
        unpack4(kv, a); unpack4(rv, b); unpack4(mv, m); unpack4(uv, r);
        float p = (a[0] + b[0]) * q[0] + (a[1] + b[1]) * q[1]
                + (a[2] + b[2]) * q[2] + (a[3] + b[3]) * q[3];
        p += __shfl_xor(p, 1); p += __shfl_xor(p, 2); p += __shfl_xor(p, 4);
        float ex = __expf(p);
        den += ex;
#pragma unroll
        for (int x = 0; x < 4; ++x) s[x] += ex * (m[x] + r[x]);
    };
    for (int c0 = 0; c0 < num; c0 += 64) {
        int nc = num - c0; if (nc > 64) nc = 64;
        if (c0 > 0) {
            sx_l = 0; tt_l = 0;
            if (lane < nc) { int2 e = el[beg + c0 + lane]; sx_l = e.x; tt_l = e.y; }
        }
        for (int i0 = 0; i0 < nc; i0 += 4) {
            const int rem = nc - i0;
            const int a0 = __shfl(sx_l, i0),     b0 = __shfl(tt_l, i0);
            const int a1 = __shfl(sx_l, i0 | 1), b1 = __shfl(tt_l, i0 | 1);
            const int a2 = __shfl(sx_l, i0 | 2), b2 = __shfl(tt_l, i0 | 2);
            const int a3 = __shfl(sx_l, i0 | 3), b3 = __shfl(tt_l, i0 | 3);
            ushort4 k0, r0, m0, u0, k1, r1, m1, u1, k2, r2, m2, u2, k3, r3, m3, u3;
            k0 = *(const ushort4*)(Kb + (size_t)a0 * 1024);
            r0 = *(const ushort4*)(Rb + (size_t)b0 * 1024);
            m0 = *(const ushort4*)(Mb + (size_t)a0 * 512);
            u0 = *(const ushort4*)(Ub + (size_t)b0 * 512);
            if (rem > 1) {
                k1 = *(const ushort4*)(Kb + (size_t)a1 * 1024);
                r1 = *(const ushort4*)(Rb + (size_t)b1 * 1024);
                m1 = *(const ushort4*)(Mb + (size_t)a1 * 512);
                u1 = *(const ushort4*)(Ub + (size_t)b1 * 512);
            }
            if (rem > 2) {
                k2 = *(const ushort4*)(Kb + (size_t)a2 * 1024);
                r2 = *(const ushort4*)(Rb + (size_t)b2 * 1024);
                m2 = *(const ushort4*)(Mb + (size_t)a2 * 512);
                u2 = *(const ushort4*)(Ub + (size_t)b2 * 512);
            }
            if (rem > 3) {
                k3 = *(const ushort4*)(Kb + (size_t)a3 * 1024);
                r3 = *(const ushort4*)(Rb + (size_t)b3 * 1024);
                m3 = *(const ushort4*)(Mb + (size_t)a3 * 512);
                u3 = *(const ushort4*)(Ub + (size_t)b3 * 512);
            }
            edge(k0, r0, m0, u0);
            if (rem > 1) edge(k1, r1, m1, u1);
            if (rem > 2) edge(k2, r2, m2, u2);
            if (rem > 3) edge(k3, r3, m3, u3);
        }
    }
    denOut = den;
}

// ---- THE fused edge kernel: blocks [0,nbblk) = type-b (longest waves first), rest type-a ----
__global__ __launch_bounds__(256) void edge_fused_kernel(
    const bf16* __restrict__ Qa1, const bf16* __restrict__ Qa2,
    const bf16* __restrict__ KMa1, const bf16* __restrict__ RKM1,
    const int2* __restrict__ meta1, const int2* __restrict__ el1,
    const bf16* __restrict__ KMb, const bf16* __restrict__ RKM2,
    const int2* __restrict__ meta2, const int2* __restrict__ el2,
    bf16* __restrict__ AGa, int NA,
    const bf16* __restrict__ Qb3, const bf16* __restrict__ Ma3, const bf16* __restrict__ RM3p,
    const int2* __restrict__ meta3, const int2* __restrict__ el3,
    bf16* __restrict__ AGb, int NB, int nbblk)
{
    const int wid = threadIdx.x >> 6, lane = threadIdx.x & 63;
    if ((int)blockIdx.x >= nbblk) {
        const int n = ((int)blockIdx.x - nbblk) * 4 + wid;
        if (n >= NA) return;
        const int2 m1 = meta1[n], m2 = meta2[n];
        const int beg1 = m1.x, num1 = m1.y, beg2 = m2.x, num2 = m2.y;
        // preload chunk-0 indices for BOTH passes (overlaps the el round-trips)
        int sx1 = 0, tt1 = 0, sx2 = 0, tt2 = 0;
        if (lane < (num1 < 64 ? num1 : 64)) { int2 e = el1[beg1 + lane]; sx1 = e.x; tt1 = e.y; }
        if (lane < (num2 < 64 ? num2 : 64)) { int2 e = el2[beg2 + lane]; sx2 = e.x; tt2 = e.y; }
        float q1[8];
        unpack8(*(const uint4*)(Qa1 + (size_t)n * 256 + (lane & 31) * 8), q1);
        const uint4 qv2 = *(const uint4*)(Qa2 + (size_t)n * 256 + (lane & 31) * 8);
        float sf[8] = {0.f, 0.f, 0.f, 0.f, 0.f, 0.f, 0.f, 0.f};
        float s[8], den;
        if (num1 > 0) {
#pragma unroll
            for (int x = 0; x < 8; ++x) s[x] = 0.f;
            epass16(KMa1, RKM1, el1, beg1, num1, sx1, tt1, q1, lane, s, den);
            float invd = 1.f / den;
#pragma unroll
            for (int x = 0; x < 8; ++x) sf[x] += s[x] * invd;
        }
        if (num2 > 0) {
            float q2[8];
            unpack8(qv2, q2);
#pragma unroll
            for (int x = 0; x < 8; ++x) s[x] = 0.f;
            epass16(KMb, RKM2, el2, beg2, num2, sx2, tt2, q2, lane, s, den);
            float invd = 1.f / den;
#pragma unroll
            for (int x = 0; x < 8; ++x) sf[x] += s[x] * invd;
        }
        float dv = 1.f / fmaxf((float)((num1 > 0) + (num2 > 0)), 1.f);
        if (lane >= 32) {
            uint4 o;
            o.x = (unsigned)f2b(eluf(sf[0] * dv)) | ((unsigned)f2b(eluf(sf[1] * dv)) << 16);
            o.y = (unsigned)f2b(eluf(sf[2] * dv)) | ((unsigned)f2b(eluf(sf[3] * dv)) << 16);
            o.z = (unsigned)f2b(eluf(sf[4] * dv)) | ((unsigned)f2b(eluf(sf[5] * dv)) << 16);
            o.w = (unsigned)f2b(eluf(sf[6] * dv)) | ((unsigned)f2b(eluf(sf[7] * dv)) << 16);
            *(uint4*)((unsigned short*)AGa + (size_t)n * 256 + (lane - 32) * 8) = o;
        }
    } else {
        const int n = (int)blockIdx.x * 4 + wid;
        if (n >= NB) return;
        const int2 m3 = meta3[n];
        const int beg3 = m3.x, num3 = m3.y;
        int sx3 = 0, tt3 = 0;
        if (lane < (num3 < 64 ? num3 : 64)) { int2 e = el3[beg3 + lane]; sx3 = e.x; tt3 = e.y; }
        float q3[4];
        unpack4(*(const ushort4*)(Qb3 + (size_t)n * 256 + lane * 4), q3);
        float s[4] = {0.f, 0.f, 0.f, 0.f};
        float den = 1.f;
        if (num3 > 0) {
            epass8(KMa1, RKM1, Ma3, RM3p, el3, beg3, num3, sx3, tt3, q3, lane, s, den);
            float invd = 1.f / den;
#pragma unroll
            for (int x = 0; x < 4; ++x) s[x] *= invd;
        }
        ushort4 o;
        o.x = f2b(eluf(s[0])); o.y = f2b(eluf(s[1]));
        o.z = f2b(eluf(s[2])); o.w = f2b(eluf(s[3]));
        *(ushort4*)((unsigned short*)AGb + (size_t)n * 256 + lane * 4) = o;
    }
}

extern "C" void kernel_launch(void* const* d_in, const int* in_sizes, int n_in,
                              void* d_out, int out_size, void* d_ws, size_t ws_size,
                              hipStream_t stream)
{
    const float* Ha   = (const float*)d_in[0];
    const float* Hb   = (const float*)d_in[1];
    const float* rte  = (const float*)d_in[2];
    const float* Wq   = (const float*)d_in[3];
    const float* Wk   = (const float*)d_in[4];
    const float* Wm   = (const float*)d_in[5];
    const float* Wa   = (const float*)d_in[6];
    const float* rteW = (const float*)d_in[7];
    const float* rteb = (const float*)d_in[8];
    const float* ln_g = (const float*)d_in[9];
    const float* ln_b = (const float*)d_in[10];
    const float* ra   = (const float*)d_in[11];
    const float* Watt = (const float*)d_in[12];
    const float* Wmsg = (const float*)d_in[13];
    const float* prior= (const float*)d_in[14];
    const int* src1 = (const int*)d_in[15];
    const int* dst1 = (const int*)d_in[16];
    const int* t1   = (const int*)d_in[17];
    const int* src2 = (const int*)d_in[18];
    const int* dst2 = (const int*)d_in[19];
    const int* t2   = (const int*)d_in[20];
    const int* src3 = (const int*)d_in[21];
    const int* dst3 = (const int*)d_in[22];
    const int* t3   = (const int*)d_in[23];

    const int NA = in_sizes[0] / 256;
    const int NB = in_sizes[1] / 256;
    const int ML = in_sizes[2] / 256;
    const int E1 = in_sizes[15];
    const int E2 = in_sizes[18];
    const int E3 = in_sizes[21];
    const int NAp = (NA + 127) & ~127;
    const int NBp = (NB + 127) & ~127;
    const int MLp = (ML + 127) & ~127;

    char* w = (char*)d_ws;
    size_t off = 0;
    auto alloc = [&](size_t bytes) -> void* {
        void* p = w + off;
        off += (bytes + 511) & ~(size_t)511;
        return p;
    };
    // weight panels
    bf16* WcatA = (bf16*)alloc((size_t)1280 * 256 * 2);  // [Wq1x|Wq2x|Wk_a|Wmx1|Wmx3]
    bf16* WcatB = (bf16*)alloc((size_t)768 * 256 * 2);   // [Wq3x|Wk_b|Wmx2]
    bf16* WcatR = (bf16*)alloc((size_t)1280 * 256 * 2);  // [Wck0|Wm1'|Wck1|Wm2'|Wm3']
    float* bcatR = (float*)alloc(1280 * 4);
    bf16* Wa_bf = (bf16*)alloc(131072 * 2);
    float* Wmx1f = (float*)alloc(65536 * 4);
    float* Wmx2f = (float*)alloc(65536 * 4);
    float* Wmx3f = (float*)alloc(65536 * 4);
    // bf16 inputs (padded rows)
    bf16* Ha_bf = (bf16*)alloc((size_t)NAp * 512);
    bf16* Hb_bf = (bf16*)alloc((size_t)NBp * 512);
    bf16* rte_bf = (bf16*)alloc((size_t)MLp * 512);
    // projections / tables (ws)
    bf16* Qa1 = (bf16*)alloc((size_t)NAp * 512);     // -> AGa (self-row rewrite)
    bf16* Qa2 = (bf16*)alloc((size_t)NAp * 512);
    bf16* KMa1 = (bf16*)alloc((size_t)NAp * 1024);   // [Ka|Ma1]
    bf16* RKM1 = (bf16*)alloc((size_t)MLp * 1024);   // [RK0|RM1']
    bf16* RKM2 = (bf16*)alloc((size_t)MLp * 1024);   // [RK1|RM2']
    bf16* RM3p = (bf16*)alloc((size_t)MLp * 512);
    bf16* AGb = (bf16*)alloc((size_t)NBp * 512);     // ws home (NOT d_out: ugemm_a's out
                                                     // writes would race it in the merged
                                                     // ugemm dispatch)
    // CSR: meta = int2{start,cnt} per node-slot, cursor separate
    int2* meta = (int2*)alloc((size_t)(NA + NA + NB) * 8);
    int2* meta1 = meta, *meta2 = meta + NA, *meta3 = meta + 2 * NA;
    int* curb = (int*)alloc((size_t)(NA + NA + NB) * 4);
    int* cur1 = curb, *cur2 = curb + NA, *cur3 = curb + 2 * NA;
    int2* elist1 = (int2*)alloc((size_t)E1 * 8);
    int2* elist2 = (int2*)alloc((size_t)E2 * 8);
    int2* elist3 = (int2*)alloc((size_t)E3 * 8);
    int* gtot = (int*)alloc(16);
    // d_out scratch: [Ma3 | Qb3 | KMb], all dead before the merged ugemm writes
    bf16* Ma3 = (bf16*)d_out;
    bf16* Qb3 = (bf16*)d_out + (size_t)NAp * 256;
    bf16* KMb = (bf16*)d_out + (size_t)NAp * 256 + (size_t)NBp * 256;   // [Kb|Mb2]
    bf16* AGa = Qa1;

    const int Etot = E1 + E2 + E3;
    const int histB = (Etot + 255) / 256;
    const int bps = (((NA > NB ? NA : NB) + 255) / 256);

    // Dispatch 0: zero meta + gtot (must precede hist3's atomics)
    zero_kernel<<<512, 256, 0, stream>>>((int*)meta, 2 * (NA + NA + NB), gtot, 4);

    // Dispatch 1: converts || fold6 || hist3 (hist last -> fills conv's tail)
    conv_fold_hist_kernel<<<4608 + histB, 256, 0, stream>>>(
        Ha, Ha_bf, NA * 32, Hb, Hb_bf, NB * 32, rte, rte_bf, ML * 32,
        Wa, Wa_bf, 16384,
        Wk, WcatA + (size_t)512 * 256, 8192,
        Wk + 65536, WcatB + (size_t)256 * 256, 8192,
        Watt, Wmsg, prior, Wq, Wm, WcatA, WcatB, Wmx1f, Wmx2f, Wmx3f,
        dst1, dst2, dst3, meta1, meta2, meta3, E1, E2, E3);

    // Dispatch 2: combine5 || alloc3b
    comb5alloc_kernel<<<1280 + bps * 3, 256, 0, stream>>>(
        Wk, Wmx1f, Wmx2f, Wmx3f, rteW, rteb, WcatR, bcatR,
        meta, curb, gtot, NA, NB, bps);

    // Dispatch 3: merged projection GEMMs (XCD-chunked swizzle) || scatter3 LAST
    const int nx0 = MLp / 128, nx1 = NAp / 128, nx2 = NBp / 128;
    const int b0 = nx0 * 10;
    const int b1 = b0 + nx1 * 10;
    const int btot = b1 + nx2 * 6;
    gemm3s_kernel<<<dim3(btot + histB), 256, 0, stream>>>(
        rte_bf, WcatR, bcatR, RKM1, RKM1 + 256, RKM2, RKM2 + 256, RM3p, 0xF, ML,
        Ha_bf, WcatA, Qa1, Qa2, KMa1, KMa1 + 256, Ma3, 0xC, NA,
        Hb_bf, WcatB, Qb3, KMb, KMb + 256, 0x6, NB,
        b0, b1, btot,
        dst1, dst2, dst3, src1, src2, src3, t1, t2, t3,
        cur1, cur2, cur3, elist1, elist2, elist3, E1, E2, E3, ML);

    // Dispatch 4: single-pass fused edge kernel (type-b blocks FIRST; AT ROOFLINE, unchanged)
    const int nablk = (NA + 3) / 4;
    const int nbblk = (NB + 3) / 4;
    edge_fused_kernel<<<dim3(nablk + nbblk), 256, 0, stream>>>(
        Qa1, Qa2, KMa1, RKM1, meta1, elist1,
        KMb, RKM2, meta2, elist2,
        AGa, NA,
        Qb3, Ma3, RM3p, meta3, elist3,
        AGb, NB, nbblk);

    // Dispatch 5: merged ugemm+LN for both node types (a blocks first, b fills tail)
    float* out = (float*)d_out;
    ugemm2_ln_kernel<<<dim3(NAp / 128 + NBp / 128), 512, 0, stream>>>(
        AGa, Wa_bf, Ha_bf, ln_g, ln_b, ra, out, NA, NAp / 128,
        AGb, Wa_bf + 65536, Hb_bf, ln_g + 256, ln_b + 256, ra + 1,
        out + (size_t)NA * 256, NB);
}

// Round 7
// 359.008 us; speedup vs baseline: 1.0333x; 1.0333x over previous
//
#include <hip/hip_runtime.h>
#include <hip/hip_bf16.h>
#include <math.h>

typedef __hip_bfloat16 bf16;
typedef __attribute__((ext_vector_type(8))) short bf16x8v;   // 8 bf16 MFMA operand
typedef __attribute__((ext_vector_type(4))) float f32x4;     // MFMA accumulator

// HGT layer, round 20 = round 19 with the XCD swizzle REVERTED (R6 evidence: swizzle cut
//   FETCH 193->31MB (6x) but gemm3s got SLOWER 115.5->125.7us -> the GEMM was never
//   fetch-bound; it is latency/structure-bound at ~20% MfmaUtil. Plain decode restored).
// Kept from R19: merged ugemm2 (one dispatch, a blocks first) + AGb in ws (safe vs
//   ugemm_a's out[0..NA) writes); scatter-last in gemm dispatch; conv||fold6||hist3.
// EDGE KERNEL AT ROOFLINE (R14-R16): replay(L3-hot)=cold ~109us; ~640MB gather/109us ~=
//   6 TB/s fabric ceiling. Untouched.
// Dispatches: [zero] [conv||fold6||hist3] [comb5||alloc3b] [gemm3 + scatter-last]
//             [edge] [ugemm a+b merged]
// Kept: int2 meta {start,cnt}; int2 CSR lists {src, ML-t}; b-blocks-first edge;
//   shfl_xor(ex,32); VGPR<=64 rule for edge (R15: 72 VGPR = occupancy cliff);
//   scatter-last (R17: scatter-first = whole-GPU atomic phase before gemm, +14us).
//   fold6:    Wq1x/Wq2x/Wq3x = blockdiag(Watt_e*prior/sqrt32)@Wq ; Wmx = blockdiagT(Wmsg)@Wm
//   combine5: RTE-table weights, panel-paired for interleaved outputs
//   gemm3:    seg0 rte->(RKM1,RKM2,RM3p); seg1 Ha->(Qa1,Qa2,KMa1,Ma3); seg2 Hb->(Qb3,KMb)
//   edge:     wave=node, ONE pass/edge-type (softmax by linearity), 4-grouped row loads.
//   ugemm_ln: x=AG@Wa^T -> u=a*x+(1-a)*H_bf -> LN -> fp32 out.
// alloc3b: atomic target must be wave-uniform (R7 lesson: divergent slot = 120k serial atomics).

__device__ __forceinline__ float eluf(float x) { return x > 0.f ? x : (__expf(x) - 1.f); }
__device__ __forceinline__ float b2f(unsigned short u) { return __uint_as_float((unsigned)u << 16); }
__device__ __forceinline__ unsigned short f2b(float f) {
    unsigned u = __float_as_uint(f);
    return (unsigned short)((u + 0x7fffu + ((u >> 16) & 1u)) >> 16);
}
__device__ __forceinline__ void unpack8(uint4 u, float* o) {
    o[0] = __uint_as_float(u.x << 16); o[1] = __uint_as_float(u.x & 0xffff0000u);
    o[2] = __uint_as_float(u.y << 16); o[3] = __uint_as_float(u.y & 0xffff0000u);
    o[4] = __uint_as_float(u.z << 16); o[5] = __uint_as_float(u.z & 0xffff0000u);
    o[6] = __uint_as_float(u.w << 16); o[7] = __uint_as_float(u.w & 0xffff0000u);
}
__device__ __forceinline__ void unpack4(ushort4 u, float* o) {
    o[0] = b2f(u.x); o[1] = b2f(u.y); o[2] = b2f(u.z); o[3] = b2f(u.w);
}

#define ASYNC_LDS16(g, l) \
    __builtin_amdgcn_global_load_lds((const __attribute__((address_space(1))) void*)(g), \
                                     (__attribute__((address_space(3))) void*)(l), 16, 0, 0)

// ---- tiny zero dispatch (must precede hist3's atomics; cannot share its dispatch) ----
__global__ void zero_kernel(int* __restrict__ z0, int nz0, int* __restrict__ z1, int nz1)
{
    for (int i = blockIdx.x * 256 + threadIdx.x; i < nz0; i += gridDim.x * 256) z0[i] = 0;
    if (blockIdx.x == 0 && threadIdx.x < (unsigned)nz1) z1[threadIdx.x] = 0;
}

// ---- merged: 6 fp32->bf16 converts (blocks 0..3071) || fold6 (3072..4607) || hist3 (rest) ----
__global__ void conv_fold_hist_kernel(
    const float* s0, bf16* o0, int n0, const float* s1, bf16* o1, int n1,
    const float* s2, bf16* o2, int n2, const float* s3, bf16* o3, int n3,
    const float* s4, bf16* o4, int n4, const float* s5, bf16* o5, int n5,
    const float* __restrict__ Watt, const float* __restrict__ Wmsg,
    const float* __restrict__ prior,
    const float* __restrict__ Wq, const float* __restrict__ Wm,
    bf16* __restrict__ WcatA, bf16* __restrict__ WcatB,
    float* __restrict__ Wmx1f, float* __restrict__ Wmx2f, float* __restrict__ Wmx3f,
    const int* __restrict__ d1, const int* __restrict__ d2, const int* __restrict__ d3,
    int2* __restrict__ m1, int2* __restrict__ m2, int2* __restrict__ m3,
    int E1, int E2, int E3)
{
    const int bid = blockIdx.x;
    if (bid < 3072) {
        // converts: 512 blocks per segment, grid-stride
        const int seg = bid >> 9;
        const int lb = bid & 511;
        const float* sp; bf16* op; int n8;
        switch (seg) {
            case 0: sp = s0; op = o0; n8 = n0; break;
            case 1: sp = s1; op = o1; n8 = n1; break;
            case 2: sp = s2; op = o2; n8 = n2; break;
            case 3: sp = s3; op = o3; n8 = n3; break;
            case 4: sp = s4; op = o4; n8 = n4; break;
            default: sp = s5; op = o5; n8 = n5; break;
        }
        for (int i = lb * 256 + threadIdx.x; i < n8; i += 512 * 256) {
            const float4* p = (const float4*)(sp + (size_t)i * 8);
            float4 a = p[0], b = p[1];
            uint4 u;
            u.x = (unsigned)f2b(a.x) | ((unsigned)f2b(a.y) << 16);
            u.y = (unsigned)f2b(a.z) | ((unsigned)f2b(a.w) << 16);
            u.z = (unsigned)f2b(b.x) | ((unsigned)f2b(b.y) << 16);
            u.w = (unsigned)f2b(b.z) | ((unsigned)f2b(b.w) << 16);
            *(uint4*)(op + (size_t)i * 8) = u;
        }
        return;
    }
    if (bid >= 4608) {
        // hist3 (last: fills conv's tail). Needs meta zeroed (zero dispatch).
        int i = (bid - 4608) * 256 + threadIdx.x;
        if (i < E1) atomicAdd(&m1[d1[i]].y, 1);
        else if (i < E1 + E2) atomicAdd(&m2[d2[i - E1]].y, 1);
        else if (i < E1 + E2 + E3) atomicAdd(&m3[d3[i - E1 - E2]].y, 1);
        return;
    }
    // fold6
    const int fb = bid - 3072;
    const int g = fb >> 8;
    const int i = fb & 255;
    const int j = threadIdx.x;
    const int h = i >> 5, r = i & 31;
    const float* A; const float* W; float sc = 1.f; int tr = 0;
    bf16* ob; float* of = nullptr;
    const float isq = 0.17677669529663687f;
    switch (g) {
        case 0: A = Watt;        sc = prior[0] * isq; W = Wq;         ob = WcatA;                       break;
        case 1: A = Watt + 1024; sc = prior[1] * isq; W = Wq;         ob = WcatA + (size_t)256 * 256;   break;
        case 2: A = Watt + 2048; sc = prior[2] * isq; W = Wq + 65536; ob = WcatB;                       break;
        case 3: A = Wmsg;        tr = 1; W = Wm;         ob = WcatA + (size_t)768 * 256;  of = Wmx1f;   break;
        case 4: A = Wmsg + 1024; tr = 1; W = Wm + 65536; ob = WcatB + (size_t)512 * 256;  of = Wmx2f;   break;
        default:A = Wmsg + 2048; tr = 1; W = Wm;         ob = WcatA + (size_t)1024 * 256; of = Wmx3f;   break;
    }
    __shared__ float arow[32];
    if (j < 32) arow[j] = (tr ? A[j * 32 + r] : A[r * 32 + j]) * sc;
    __syncthreads();
    float acc = 0.f;
    for (int k = 0; k < 32; ++k) acc += arow[k] * W[(size_t)(h * 32 + k) * 256 + j];
    ((unsigned short*)ob)[(size_t)i * 256 + j] = f2b(acc);
    if (of) of[(size_t)i * 256 + j] = acc;
}

// ---- merged: 5 RTE-weight combines (blocks 0..1279) || alloc3b (rest) ----
__global__ void comb5alloc_kernel(const float* __restrict__ Wk,
                                  const float* __restrict__ Wmx1f, const float* __restrict__ Wmx2f,
                                  const float* __restrict__ Wmx3f,
                                  const float* __restrict__ rteW, const float* __restrict__ rteb,
                                  bf16* __restrict__ WcatR, float* __restrict__ bcatR,
                                  int2* __restrict__ meta, int* __restrict__ cursor,
                                  int* __restrict__ gtot, int NA, int NB, int bps)
{
    if (blockIdx.x >= 1280) {
        // alloc3b: needs meta.y (prev dispatch) + gtot zeroed
        const int lid = (int)blockIdx.x - 1280;
        const int slot = lid / bps;
        const int base = (slot == 0) ? 0 : (slot == 1) ? NA : 2 * NA;
        const int len = (slot == 2) ? NB : NA;
        int i = (lid % bps) * 256 + threadIdx.x;
        if (i >= len) return;
        int* gp = gtot + slot;         // uniform across the block -> wave-reduced atomics
        int idx = base + i;
        int s = atomicAdd(gp, meta[idx].y);
        meta[idx].x = s; cursor[idx] = s;
        return;
    }
    const int g = blockIdx.x >> 8;
    const int i = blockIdx.x & 255;
    const int j = threadIdx.x;
    const float* Wp; const float* rW; const float* rb; int op;
    switch (g) {
        case 0: Wp = Wk;         rW = rteW;         rb = rteb;       op = 0; break;
        case 1: Wp = Wk + 65536; rW = rteW + 65536; rb = rteb + 256; op = 2; break;
        case 2: Wp = Wmx1f;      rW = rteW;         rb = rteb;       op = 1; break;
        case 3: Wp = Wmx2f;      rW = rteW + 65536; rb = rteb + 256; op = 3; break;
        default:Wp = Wmx3f;      rW = rteW;         rb = rteb;       op = 4; break;
    }
    __shared__ float wrow[256];
    wrow[j] = Wp[i * 256 + j];
    __syncthreads();
    float acc = 0.f;
    for (int k = 0; k < 256; ++k) acc += wrow[k] * rW[k * 256 + j];
    ((unsigned short*)WcatR)[(size_t)(op * 256 + i) * 256 + j] = f2b(acc);
    if (j == 0) {
        float b = 0.f;
        for (int k = 0; k < 256; ++k) b += wrow[k] * rb[k];
        bcatR[op * 256 + i] = b;
    }
}

// ---- shared MFMA GEMM body: C{0..4} = A@Wcat^T (+bcat); stride-masked outputs ----
__device__ __forceinline__ void gemm_body(
    const bf16* __restrict__ A, const bf16* __restrict__ Wcat,
    const float* __restrict__ bcat,
    bf16* C0, bf16* C1, bf16* C2, bf16* C3, bf16* C4,
    int wideMask, int M, int bx, int by, char* As, char* Bs)
{
    const int tid = threadIdx.x;
    const int wid = tid >> 6, lane = tid & 63;
    const size_t row0 = (size_t)bx * 128;
    const int gcol0 = by * 128;
    const int cb = by >> 1;
    const int lcol0 = (by & 1) * 128;
    bf16* Csel = (cb == 0) ? C0 : (cb == 1) ? C1 : (cb == 2) ? C2 : (cb == 3) ? C3 : C4;
    const size_t cstride = ((wideMask >> cb) & 1) ? 512 : 256;
    const int wr = wid >> 1, wc = wid & 1;

    f32x4 zero = {0.f, 0.f, 0.f, 0.f};
    f32x4 acc[4][4];
#pragma unroll
    for (int m = 0; m < 4; ++m)
#pragma unroll
        for (int n = 0; n < 4; ++n) acc[m][n] = zero;

    const int sr = wid * 32 + (lane >> 3);
    const int scc = (lane & 7) << 4;
    const char* Ab = (const char*)A;
    const char* Wb = (const char*)Wcat;

    for (int k0 = 0; k0 < 512; k0 += 128) {
#pragma unroll
        for (int i = 0; i < 4; ++i) {
            const int r = sr + i * 8;
            const int csw = scc ^ ((r & 7) << 4);
            const int ldso = wid * 4096 + i * 1024;
            ASYNC_LDS16(Ab + (row0 + r) * 512 + k0 + csw, As + ldso);
            ASYNC_LDS16(Wb + (size_t)(gcol0 + r) * 512 + k0 + csw, Bs + ldso);
        }
        __syncthreads();
#pragma unroll
        for (int kk = 0; kk < 2; ++kk) {
            bf16x8v a[4], b[4];
            const int cbase = kk * 64 + ((lane >> 4) << 4);
#pragma unroll
            for (int m = 0; m < 4; ++m) {
                const int r = wr * 64 + m * 16 + (lane & 15);
                a[m] = *(const bf16x8v*)(As + r * 128 + (cbase ^ ((r & 7) << 4)));
            }
#pragma unroll
            for (int n = 0; n < 4; ++n) {
                const int r = wc * 64 + n * 16 + (lane & 15);
                b[n] = *(const bf16x8v*)(Bs + r * 128 + (cbase ^ ((r & 7) << 4)));
            }
#pragma unroll
            for (int m = 0; m < 4; ++m)
#pragma unroll
                for (int n = 0; n < 4; ++n)
                    acc[m][n] = __builtin_amdgcn_mfma_f32_16x16x32_bf16(a[m], b[n], acc[m][n], 0, 0, 0);
        }
        __syncthreads();
    }
    const int orow = (lane >> 4) << 2;
    const int ocol = lane & 15;
    float bv[4];
#pragma unroll
    for (int n = 0; n < 4; ++n)
        bv[n] = bcat ? bcat[gcol0 + wc * 64 + n * 16 + ocol] : 0.f;
    unsigned short* Cp = (unsigned short*)Csel;
#pragma unroll
    for (int m = 0; m < 4; ++m) {
#pragma unroll
        for (int j = 0; j < 4; ++j) {
            const size_t row = row0 + wr * 64 + m * 16 + orow + j;
            if ((int)row >= M) continue;
#pragma unroll
            for (int n = 0; n < 4; ++n) {
                const int col = lcol0 + wc * 64 + n * 16 + ocol;
                Cp[row * cstride + col] = f2b(acc[m][n][j] + bv[n]);
            }
        }
    }
}

// ---- merged: 3-segment GEMM (plain column-fastest decode) || scatter3 LAST.
// R6 lesson: XCD swizzle cut FETCH 6x but slowed the kernel (not fetch-bound) -> plain.
// Scatter blocks fill the gemm drain tail (R17 lesson: scatter-first serializes).
__global__ __launch_bounds__(256) void gemm3s_kernel(
    const bf16* A0, const bf16* W0, const float* bc0,
    bf16* o00, bf16* o01, bf16* o02, bf16* o03, bf16* o04, int mask0, int M0,
    const bf16* A1, const bf16* W1,
    bf16* o10, bf16* o11, bf16* o12, bf16* o13, bf16* o14, int mask1, int M1,
    const bf16* A2, const bf16* W2,
    bf16* o20, bf16* o21, bf16* o22, int mask2, int M2,
    int b0, int b1, int btot,
    const int* __restrict__ d1, const int* __restrict__ d2, const int* __restrict__ d3,
    const int* __restrict__ s1, const int* __restrict__ s2, const int* __restrict__ s3,
    const int* __restrict__ tv1, const int* __restrict__ tv2, const int* __restrict__ tv3,
    int* __restrict__ cur1, int* __restrict__ cur2, int* __restrict__ cur3,
    int2* __restrict__ el1, int2* __restrict__ el2, int2* __restrict__ el3,
    int E1, int E2, int E3, int ml)
{
    __shared__ __align__(16) char As[16384];
    __shared__ __align__(16) char Bs[16384];
    const int bid = blockIdx.x;
    if (bid >= btot) {
        // scatter3: needs cursors (prev dispatch); completes before edge (dispatch boundary)
        int i = (bid - btot) * 256 + threadIdx.x;
        if (i < E1) {
            int p = atomicAdd(&cur1[d1[i]], 1);
            el1[p] = make_int2(s1[i], ml - tv1[i]);
        } else if (i < E1 + E2) {
            int e = i - E1; int p = atomicAdd(&cur2[d2[e]], 1);
            el2[p] = make_int2(s2[e], ml - tv2[e]);
        } else if (i < E1 + E2 + E3) {
            int e = i - E1 - E2; int p = atomicAdd(&cur3[d3[e]], 1);
            el3[p] = make_int2(s3[e], ml - tv3[e]);
        }
        return;
    }
    if (bid < b0) {
        gemm_body(A0, W0, bc0, o00, o01, o02, o03, o04, mask0, M0,
                  bid / 10, bid % 10, As, Bs);
    } else if (bid < b1) {
        const int lid = bid - b0;
        gemm_body(A1, W1, nullptr, o10, o11, o12, o13, o14, mask1, M1,
                  lid / 10, lid % 10, As, Bs);
    } else {
        const int lid = bid - b1;
        gemm_body(A2, W2, nullptr, o20, o21, o22, o22, o22, mask2, M2,
                  lid / 6, lid % 6, As, Bs);
    }
}

// ---- fused update-GEMM + LayerNorm body ----
__device__ __forceinline__ void ugemm_ln_body(
    const bf16* __restrict__ AG, const bf16* __restrict__ Wp,
    const bf16* __restrict__ Hbf, const float* __restrict__ g,
    const float* __restrict__ b, const float* __restrict__ ra,
    float* __restrict__ out, int M, int bx,
    char* As, char* Bs, float (*red)[8])
{
    const int tid = threadIdx.x;
    const int wid = tid >> 6, lane = tid & 63;
    const int wr = wid >> 2, wc = wid & 3;
    const size_t row0 = (size_t)bx * 128;

    f32x4 zero = {0.f, 0.f, 0.f, 0.f};
    f32x4 acc[4][4];
#pragma unroll
    for (int m = 0; m < 4; ++m)
#pragma unroll
        for (int n = 0; n < 4; ++n) acc[m][n] = zero;

    const char* Ab = (const char*)AG;
    const char* Wb = (const char*)Wp;
    for (int k0 = 0; k0 < 512; k0 += 128) {
#pragma unroll
        for (int i = 0; i < 2; ++i) {
            const int r = wid * 16 + i * 8 + (lane >> 3);
            const int csw = ((lane & 7) << 4) ^ ((r & 7) << 4);
            ASYNC_LDS16(Ab + (row0 + r) * 512 + k0 + csw, As + (wid * 16 + i * 8) * 128);
        }
#pragma unroll
        for (int i = 0; i < 4; ++i) {
            const int r = wid * 32 + i * 8 + (lane >> 3);
            const int csw = ((lane & 7) << 4) ^ ((r & 7) << 4);
            ASYNC_LDS16(Wb + (size_t)r * 512 + k0 + csw, Bs + (wid * 32 + i * 8) * 128);
        }
        __syncthreads();
#pragma unroll
        for (int kk = 0; kk < 2; ++kk) {
            bf16x8v a[4], bv[4];
            const int cbase = kk * 64 + ((lane >> 4) << 4);
#pragma unroll
            for (int m = 0; m < 4; ++m) {
                const int r = wr * 64 + m * 16 + (lane & 15);
                a[m] = *(const bf16x8v*)(As + r * 128 + (cbase ^ ((r & 7) << 4)));
            }
#pragma unroll
            for (int n = 0; n < 4; ++n) {
                const int r = wc * 64 + n * 16 + (lane & 15);
                bv[n] = *(const bf16x8v*)(Bs + r * 128 + (cbase ^ ((r & 7) << 4)));
            }
#pragma unroll
            for (int m = 0; m < 4; ++m)
#pragma unroll
                for (int n = 0; n < 4; ++n)
                    acc[m][n] = __builtin_amdgcn_mfma_f32_16x16x32_bf16(a[m], bv[n], acc[m][n], 0, 0, 0);
        }
        __syncthreads();
    }
    const float alpha = 1.f / (1.f + __expf(-ra[0]));
    const float beta = 1.f - alpha;
    const int orow = (lane >> 4) << 2;
    const int ocol = lane & 15;
    float gv[4], bb[4];
#pragma unroll
    for (int n = 0; n < 4; ++n) {
        gv[n] = g[wc * 64 + n * 16 + ocol];
        bb[n] = b[wc * 64 + n * 16 + ocol];
    }
    const unsigned short* Hp = (const unsigned short*)Hbf;
#pragma unroll
    for (int m = 0; m < 4; ++m) {
#pragma unroll
        for (int j = 0; j < 4; ++j) {
            const int rl = wr * 64 + m * 16 + orow + j;
            const size_t grow = row0 + rl;
            float s = 0.f, s2 = 0.f;
#pragma unroll
            for (int n = 0; n < 4; ++n) {
                const int col = wc * 64 + n * 16 + ocol;
                float hv = ((int)grow < M) ? b2f(Hp[grow * 256 + col]) : 0.f;
                float u = alpha * acc[m][n][j] + beta * hv;
                acc[m][n][j] = u;
                s += u; s2 += u * u;
            }
            s += __shfl_xor(s, 1); s2 += __shfl_xor(s2, 1);
            s += __shfl_xor(s, 2); s2 += __shfl_xor(s2, 2);
            s += __shfl_xor(s, 4); s2 += __shfl_xor(s2, 4);
            s += __shfl_xor(s, 8); s2 += __shfl_xor(s2, 8);
            if (ocol == 0) { red[rl][wc] = s; red[rl][4 + wc] = s2; }
        }
    }
    __syncthreads();
#pragma unroll
    for (int m = 0; m < 4; ++m) {
#pragma unroll
        for (int j = 0; j < 4; ++j) {
            const int rl = wr * 64 + m * 16 + orow + j;
            const size_t grow = row0 + rl;
            if ((int)grow >= M) continue;
            float S = red[rl][0] + red[rl][1] + red[rl][2] + red[rl][3];
            float S2 = red[rl][4] + red[rl][5] + red[rl][6] + red[rl][7];
            const float mu = S * 0.00390625f;
            const float var = S2 * 0.00390625f - mu * mu;
            const float inv = rsqrtf(var + 1e-5f);
#pragma unroll
            for (int n = 0; n < 4; ++n) {
                const int col = wc * 64 + n * 16 + ocol;
                out[grow * 256 + col] = (acc[m][n][j] - mu) * inv * gv[n] + bb[n];
            }
        }
    }
}

// ---- merged ugemm+LN for BOTH node types in one dispatch (a blocks first) ----
// SAFE only because AGb lives in ws, not under ugemm_a's out[0..NA) writes.
__global__ __launch_bounds__(512) void ugemm2_ln_kernel(
    const bf16* AGa, const bf16* Wpa, const bf16* Ha_bf, const float* ga,
    const float* ba, const float* raa, float* outa, int Ma, int nba,
    const bf16* AGb, const bf16* Wpb, const bf16* Hb_bf, const float* gb,
    const float* bb, const float* rab, float* outb, int Mb)
{
    __shared__ __align__(16) char As[16384];
    __shared__ __align__(16) char Bs[32768];
    __shared__ float red[128][8];
    const int bid = blockIdx.x;
    if (bid < nba) {
        ugemm_ln_body(AGa, Wpa, Ha_bf, ga, ba, raa, outa, Ma, bid, As, Bs, red);
    } else {
        ugemm_ln_body(AGb, Wpb, Hb_bf, gb, bb, rab, outb, Mb, bid - nba, As, Bs, red);
    }
}

// ---- single-pass edge accumulate, interleaved rows (type-a edge types) ----
// 4-grouped row loads (R14 structure, VGPR-safe).
__device__ __forceinline__ void epass16(
    const bf16* __restrict__ KM, const bf16* __restrict__ RKM,
    const int2* __restrict__ el, int beg, int num,
    int sx_l, int tt_l,                      // preloaded chunk-0 indices (per-lane)
    const float q[8], int lane,
    float s[8], float& denOut)
{
    float den = 0.f;
    const char* KMb = (const char*)KM + lane * 16;
    const char* RMb = (const char*)RKM + lane * 16;
    auto edge = [&](uint4 km, uint4 rm) {
        float a[8], b[8];
        unpack8(km, a); unpack8(rm, b);
#pragma unroll
        for (int x = 0; x < 8; ++x) a[x] += b[x];
        float p = a[0] * q[0] + a[1] * q[1] + a[2] * q[2] + a[3] * q[3]
                + a[4] * q[4] + a[5] * q[5] + a[6] * q[6] + a[7] * q[7];
        p += __shfl_xor(p, 1); p += __shfl_xor(p, 2);
        float ex = __expf(p);
        float exb = __shfl_xor(ex, 32);   // lane 32+i <- lane i's reduced ex (lanes<32: unused)
        den += exb;
#pragma unroll
        for (int x = 0; x < 8; ++x) s[x] += exb * a[x];   // meaningful on M lanes only
    };
    for (int c0 = 0; c0 < num; c0 += 64) {
        int nc = num - c0; if (nc > 64) nc = 64;
        if (c0 > 0) {
            sx_l = 0; tt_l = 0;
            if (lane < nc) { int2 e = el[beg + c0 + lane]; sx_l = e.x; tt_l = e.y; }
        }
        for (int i0 = 0; i0 < nc; i0 += 4) {
            const int rem = nc - i0;
            const int a0 = __shfl(sx_l, i0),     b0 = __shfl(tt_l, i0);
            const int a1 = __shfl(sx_l, i0 | 1), b1 = __shfl(tt_l, i0 | 1);
            const int a2 = __shfl(sx_l, i0 | 2), b2 = __shfl(tt_l, i0 | 2);
            const int a3 = __shfl(sx_l, i0 | 3), b3 = __shfl(tt_l, i0 | 3);
            uint4 km0, rm0, km1, rm1, km2, rm2, km3, rm3;
            km0 = *(const uint4*)(KMb + (size_t)a0 * 1024);
            rm0 = *(const uint4*)(RMb + (size_t)b0 * 1024);
            if (rem > 1) {
                km1 = *(const uint4*)(KMb + (size_t)a1 * 1024);
                rm1 = *(const uint4*)(RMb + (size_t)b1 * 1024);
            }
            if (rem > 2) {
                km2 = *(const uint4*)(KMb + (size_t)a2 * 1024);
                rm2 = *(const uint4*)(RMb + (size_t)b2 * 1024);
            }
            if (rem > 3) {
                km3 = *(const uint4*)(KMb + (size_t)a3 * 1024);
                rm3 = *(const uint4*)(RMb + (size_t)b3 * 1024);
            }
            edge(km0, rm0);
            if (rem > 1) edge(km1, rm1);
            if (rem > 2) edge(km2, rm2);
            if (rem > 3) edge(km3, rm3);
        }
    }
    denOut = den;
}

// ---- single-pass edge accumulate, split rows (e3), 4-grouped ----
__device__ __forceinline__ void epass8(
    const bf16* __restrict__ Kh, const bf16* __restrict__ RKh,   // K halves, stride 512 el
    const bf16* __restrict__ Mt, const bf16* __restrict__ RMt,   // stride 256 el
    const int2* __restrict__ el, int beg, int num,
    int sx_l, int tt_l,
    const float q[4], int lane,
    float s[4], float& denOut)
{
    float den = 0.f;
    const char* Kb = (const char*)Kh + lane * 8;
    const char* Rb = (const char*)RKh + lane * 8;
    const char* Mb = (const char*)Mt + lane * 8;
    const char* Ub = (const char*)RMt + lane * 8;
    auto edge = [&](ushort4 kv, ushort4 rv, ushort4 mv, ushort4 uv) {
        float a[4], b[4], m[4], r[4];
        unpack4(kv, a); unpack4(rv, b); unpack4(mv, m); unpack4(uv, r);
        float p = (a[0] + b[0]) * q[0] + (a[1] + b[1]) * q[1]
                + (a[2] + b[2]) * q[2] + (a[3] + b[3]) * q[3];
        p += __shfl_xor(p, 1); p += __shfl_xor(p, 2); p += __shfl_xor(p, 4);
        float ex = __expf(p);
        den += ex;
#pragma unroll
        for (int x = 0; x < 4; ++x) s[x] += ex * (m[x] + r[x]);
    };
    for (int c0 = 0; c0 < num; c0 += 64) {
        int nc = num - c0; if (nc > 64) nc = 64;
        if (c0 > 0) {
            sx_l = 0; tt_l = 0;
            if (lane < nc) { int2 e = el[beg + c0 + lane]; sx_l = e.x; tt_l = e.y; }
        }
        for (int i0 = 0; i0 < nc; i0 += 4) {
            const int rem = nc - i0;
            const int a0 = __shfl(sx_l, i0),     b0 = __shfl(tt_l, i0);
            const int a1 = __shfl(sx_l, i0 | 1), b1 = __shfl(tt_l, i0 | 1);
            const int a2 = __shfl(sx_l, i0 | 2), b2 = __shfl(tt_l, i0 | 2);
            const int a3 = __shfl(sx_l, i0 | 3), b3 = __shfl(tt_l, i0 | 3);
            ushort4 k0, r0, m0, u0, k1, r1, m1, u1, k2, r2, m2, u2, k3, r3, m3, u3;
            k0 = *(const ushort4*)(Kb + (size_t)a0 * 1024);
            r0 = *(const ushort4*)(Rb + (size_t)b0 * 1024);
            m0 = *(const ushort4*)(Mb + (size_t)a0 * 512);
            u0 = *(const ushort4*)(Ub + (size_t)b0 * 512);
            if (rem > 1) {
                k1 = *(const ushort4*)(Kb + (size_t)a1 * 1024);
                r1 = *(const ushort4*)(Rb + (size_t)b1 * 1024);
                m1 = *(const ushort4*)(Mb + (size_t)a1 * 512);
                u1 = *(const ushort4*)(Ub + (size_t)b1 * 512);
            }
            if (rem > 2) {
                k2 = *(const ushort4*)(Kb + (size_t)a2 * 1024);
                r2 = *(const ushort4*)(Rb + (size_t)b2 * 1024);
                m2 = *(const ushort4*)(Mb + (size_t)a2 * 512);
                u2 = *(const ushort4*)(Ub + (size_t)b2 * 512);
            }
            if (rem > 3) {
                k3 = *(const ushort4*)(Kb + (size_t)a3 * 1024);
                r3 = *(const ushort4*)(Rb + (size_t)b3 * 1024);
                m3 = *(const ushort4*)(Mb + (size_t)a3 * 512);
                u3 = *(const ushort4*)(Ub + (size_t)b3 * 512);
            }
            edge(k0, r0, m0, u0);
            if (rem > 1) edge(k1, r1, m1, u1);
            if (rem > 2) edge(k2, r2, m2, u2);
            if (rem > 3) edge(k3, r3, m3, u3);
        }
    }
    denOut = den;
}

// ---- THE fused edge kernel: blocks [0,nbblk) = type-b (longest waves first), rest type-a ----
__global__ __launch_bounds__(256) void edge_fused_kernel(
    const bf16* __restrict__ Qa1, const bf16* __restrict__ Qa2,
    const bf16* __restrict__ KMa1, const bf16* __restrict__ RKM1,
    const int2* __restrict__ meta1, const int2* __restrict__ el1,
    const bf16* __restrict__ KMb, const bf16* __restrict__ RKM2,
    const int2* __restrict__ meta2, const int2* __restrict__ el2,
    bf16* __restrict__ AGa, int NA,
    const bf16* __restrict__ Qb3, const bf16* __restrict__ Ma3, const bf16* __restrict__ RM3p,
    const int2* __restrict__ meta3, const int2* __restrict__ el3,
    bf16* __restrict__ AGb, int NB, int nbblk)
{
    const int wid = threadIdx.x >> 6, lane = threadIdx.x & 63;
    if ((int)blockIdx.x >= nbblk) {
        const int n = ((int)blockIdx.x - nbblk) * 4 + wid;
        if (n >= NA) return;
        const int2 m1 = meta1[n], m2 = meta2[n];
        const int beg1 = m1.x, num1 = m1.y, beg2 = m2.x, num2 = m2.y;
        // preload chunk-0 indices for BOTH passes (overlaps the el round-trips)
        int sx1 = 0, tt1 = 0, sx2 = 0, tt2 = 0;
        if (lane < (num1 < 64 ? num1 : 64)) { int2 e = el1[beg1 + lane]; sx1 = e.x; tt1 = e.y; }
        if (lane < (num2 < 64 ? num2 : 64)) { int2 e = el2[beg2 + lane]; sx2 = e.x; tt2 = e.y; }
        float q1[8];
        unpack8(*(const uint4*)(Qa1 + (size_t)n * 256 + (lane & 31) * 8), q1);
        const uint4 qv2 = *(const uint4*)(Qa2 + (size_t)n * 256 + (lane & 31) * 8);
        float sf[8] = {0.f, 0.f, 0.f, 0.f, 0.f, 0.f, 0.f, 0.f};
        float s[8], den;
        if (num1 > 0) {
#pragma unroll
            for (int x = 0; x < 8; ++x) s[x] = 0.f;
            epass16(KMa1, RKM1, el1, beg1, num1, sx1, tt1, q1, lane, s, den);
            float invd = 1.f / den;
#pragma unroll
            for (int x = 0; x < 8; ++x) sf[x] += s[x] * invd;
        }
        if (num2 > 0) {
            float q2[8];
            unpack8(qv2, q2);
#pragma unroll
            for (int x = 0; x < 8; ++x) s[x] = 0.f;
            epass16(KMb, RKM2, el2, beg2, num2, sx2, tt2, q2, lane, s, den);
            float invd = 1.f / den;
#pragma unroll
            for (int x = 0; x < 8; ++x) sf[x] += s[x] * invd;
        }
        float dv = 1.f / fmaxf((float)((num1 > 0) + (num2 > 0)), 1.f);
        if (lane >= 32) {
            uint4 o;
            o.x = (unsigned)f2b(eluf(sf[0] * dv)) | ((unsigned)f2b(eluf(sf[1] * dv)) << 16);
            o.y = (unsigned)f2b(eluf(sf[2] * dv)) | ((unsigned)f2b(eluf(sf[3] * dv)) << 16);
            o.z = (unsigned)f2b(eluf(sf[4] * dv)) | ((unsigned)f2b(eluf(sf[5] * dv)) << 16);
            o.w = (unsigned)f2b(eluf(sf[6] * dv)) | ((unsigned)f2b(eluf(sf[7] * dv)) << 16);
            *(uint4*)((unsigned short*)AGa + (size_t)n * 256 + (lane - 32) * 8) = o;
        }
    } else {
        const int n = (int)blockIdx.x * 4 + wid;
        if (n >= NB) return;
        const int2 m3 = meta3[n];
        const int beg3 = m3.x, num3 = m3.y;
        int sx3 = 0, tt3 = 0;
        if (lane < (num3 < 64 ? num3 : 64)) { int2 e = el3[beg3 + lane]; sx3 = e.x; tt3 = e.y; }
        float q3[4];
        unpack4(*(const ushort4*)(Qb3 + (size_t)n * 256 + lane * 4), q3);
        float s[4] = {0.f, 0.f, 0.f, 0.f};
        float den = 1.f;
        if (num3 > 0) {
            epass8(KMa1, RKM1, Ma3, RM3p, el3, beg3, num3, sx3, tt3, q3, lane, s, den);
            float invd = 1.f / den;
#pragma unroll
            for (int x = 0; x < 4; ++x) s[x] *= invd;
        }
        ushort4 o;
        o.x = f2b(eluf(s[0])); o.y = f2b(eluf(s[1]));
        o.z = f2b(eluf(s[2])); o.w = f2b(eluf(s[3]));
        *(ushort4*)((unsigned short*)AGb + (size_t)n * 256 + lane * 4) = o;
    }
}

extern "C" void kernel_launch(void* const* d_in, const int* in_sizes, int n_in,
                              void* d_out, int out_size, void* d_ws, size_t ws_size,
                              hipStream_t stream)
{
    const float* Ha   = (const float*)d_in[0];
    const float* Hb   = (const float*)d_in[1];
    const float* rte  = (const float*)d_in[2];
    const float* Wq   = (const float*)d_in[3];
    const float* Wk   = (const float*)d_in[4];
    const float* Wm   = (const float*)d_in[5];
    const float* Wa   = (const float*)d_in[6];
    const float* rteW = (const float*)d_in[7];
    const float* rteb = (const float*)d_in[8];
    const float* ln_g = (const float*)d_in[9];
    const float* ln_b = (const float*)d_in[10];
    const float* ra   = (const float*)d_in[11];
    const float* Watt = (const float*)d_in[12];
    const float* Wmsg = (const float*)d_in[13];
    const float* prior= (const float*)d_in[14];
    const int* src1 = (const int*)d_in[15];
    const int* dst1 = (const int*)d_in[16];
    const int* t1   = (const int*)d_in[17];
    const int* src2 = (const int*)d_in[18];
    const int* dst2 = (const int*)d_in[19];
    const int* t2   = (const int*)d_in[20];
    const int* src3 = (const int*)d_in[21];
    const int* dst3 = (const int*)d_in[22];
    const int* t3   = (const int*)d_in[23];

    const int NA = in_sizes[0] / 256;
    const int NB = in_sizes[1] / 256;
    const int ML = in_sizes[2] / 256;
    const int E1 = in_sizes[15];
    const int E2 = in_sizes[18];
    const int E3 = in_sizes[21];
    const int NAp = (NA + 127) & ~127;
    const int NBp = (NB + 127) & ~127;
    const int MLp = (ML + 127) & ~127;

    char* w = (char*)d_ws;
    size_t off = 0;
    auto alloc = [&](size_t bytes) -> void* {
        void* p = w + off;
        off += (bytes + 511) & ~(size_t)511;
        return p;
    };
    // weight panels
    bf16* WcatA = (bf16*)alloc((size_t)1280 * 256 * 2);  // [Wq1x|Wq2x|Wk_a|Wmx1|Wmx3]
    bf16* WcatB = (bf16*)alloc((size_t)768 * 256 * 2);   // [Wq3x|Wk_b|Wmx2]
    bf16* WcatR = (bf16*)alloc((size_t)1280 * 256 * 2);  // [Wck0|Wm1'|Wck1|Wm2'|Wm3']
    float* bcatR = (float*)alloc(1280 * 4);
    bf16* Wa_bf = (bf16*)alloc(131072 * 2);
    float* Wmx1f = (float*)alloc(65536 * 4);
    float* Wmx2f = (float*)alloc(65536 * 4);
    float* Wmx3f = (float*)alloc(65536 * 4);
    // bf16 inputs (padded rows)
    bf16* Ha_bf = (bf16*)alloc((size_t)NAp * 512);
    bf16* Hb_bf = (bf16*)alloc((size_t)NBp * 512);
    bf16* rte_bf = (bf16*)alloc((size_t)MLp * 512);
    // projections / tables (ws)
    bf16* Qa1 = (bf16*)alloc((size_t)NAp * 512);     // -> AGa (self-row rewrite)
    bf16* Qa2 = (bf16*)alloc((size_t)NAp * 512);
    bf16* KMa1 = (bf16*)alloc((size_t)NAp * 1024);   // [Ka|Ma1]
    bf16* RKM1 = (bf16*)alloc((size_t)MLp * 1024);   // [RK0|RM1']
    bf16* RKM2 = (bf16*)alloc((size_t)MLp * 1024);   // [RK1|RM2']
    bf16* RM3p = (bf16*)alloc((size_t)MLp * 512);
    bf16* AGb = (bf16*)alloc((size_t)NBp * 512);     // ws home (NOT d_out: ugemm_a's out
                                                     // writes would race it in the merged
                                                     // ugemm dispatch)
    // CSR: meta = int2{start,cnt} per node-slot, cursor separate
    int2* meta = (int2*)alloc((size_t)(NA + NA + NB) * 8);
    int2* meta1 = meta, *meta2 = meta + NA, *meta3 = meta + 2 * NA;
    int* curb = (int*)alloc((size_t)(NA + NA + NB) * 4);
    int* cur1 = curb, *cur2 = curb + NA, *cur3 = curb + 2 * NA;
    int2* elist1 = (int2*)alloc((size_t)E1 * 8);
    int2* elist2 = (int2*)alloc((size_t)E2 * 8);
    int2* elist3 = (int2*)alloc((size_t)E3 * 8);
    int* gtot = (int*)alloc(16);
    // d_out scratch: [Ma3 | Qb3 | KMb], all dead before the merged ugemm writes
    bf16* Ma3 = (bf16*)d_out;
    bf16* Qb3 = (bf16*)d_out + (size_t)NAp * 256;
    bf16* KMb = (bf16*)d_out + (size_t)NAp * 256 + (size_t)NBp * 256;   // [Kb|Mb2]
    bf16* AGa = Qa1;

    const int Etot = E1 + E2 + E3;
    const int histB = (Etot + 255) / 256;
    const int bps = (((NA > NB ? NA : NB) + 255) / 256);

    // Dispatch 0: zero meta + gtot (must precede hist3's atomics)
    zero_kernel<<<512, 256, 0, stream>>>((int*)meta, 2 * (NA + NA + NB), gtot, 4);

    // Dispatch 1: converts || fold6 || hist3 (hist last -> fills conv's tail)
    conv_fold_hist_kernel<<<4608 + histB, 256, 0, stream>>>(
        Ha, Ha_bf, NA * 32, Hb, Hb_bf, NB * 32, rte, rte_bf, ML * 32,
        Wa, Wa_bf, 16384,
        Wk, WcatA + (size_t)512 * 256, 8192,
        Wk + 65536, WcatB + (size_t)256 * 256, 8192,
        Watt, Wmsg, prior, Wq, Wm, WcatA, WcatB, Wmx1f, Wmx2f, Wmx3f,
        dst1, dst2, dst3, meta1, meta2, meta3, E1, E2, E3);

    // Dispatch 2: combine5 || alloc3b
    comb5alloc_kernel<<<1280 + bps * 3, 256, 0, stream>>>(
        Wk, Wmx1f, Wmx2f, Wmx3f, rteW, rteb, WcatR, bcatR,
        meta, curb, gtot, NA, NB, bps);

    // Dispatch 3: merged projection GEMMs (plain decode) || scatter3 LAST
    const int nx0 = MLp / 128, nx1 = NAp / 128, nx2 = NBp / 128;
    const int b0 = nx0 * 10;
    const int b1 = b0 + nx1 * 10;
    const int btot = b1 + nx2 * 6;
    gemm3s_kernel<<<dim3(btot + histB), 256, 0, stream>>>(
        rte_bf, WcatR, bcatR, RKM1, RKM1 + 256, RKM2, RKM2 + 256, RM3p, 0xF, ML,
        Ha_bf, WcatA, Qa1, Qa2, KMa1, KMa1 + 256, Ma3, 0xC, NA,
        Hb_bf, WcatB, Qb3, KMb, KMb + 256, 0x6, NB,
        b0, b1, btot,
        dst1, dst2, dst3, src1, src2, src3, t1, t2, t3,
        cur1, cur2, cur3, elist1, elist2, elist3, E1, E2, E3, ML);

    // Dispatch 4: single-pass fused edge kernel (type-b blocks FIRST; AT ROOFLINE, unchanged)
    const int nablk = (NA + 3) / 4;
    const int nbblk = (NB + 3) / 4;
    edge_fused_kernel<<<dim3(nablk + nbblk), 256, 0, stream>>>(
        Qa1, Qa2, KMa1, RKM1, meta1, elist1,
        KMb, RKM2, meta2, elist2,
        AGa, NA,
        Qb3, Ma3, RM3p, meta3, elist3,
        AGb, NB, nbblk);

    // Dispatch 5: merged ugemm+LN for both node types (a blocks first, b fills tail)
    float* out = (float*)d_out;
    ugemm2_ln_kernel<<<dim3(NAp / 128 + NBp / 128), 512, 0, stream>>>(
        AGa, Wa_bf, Ha_bf, ln_g, ln_b, ra, out, NA, NAp / 128,
        AGb, Wa_bf + 65536, Hb_bf, ln_g + 256, ln_b + 256, ra + 1,
        out + (size_t)NA * 256, NB);
}

// Round 8
// 347.254 us; speedup vs baseline: 1.0683x; 1.0338x over previous
//
#include <hip/hip_runtime.h>
#include <hip/hip_bf16.h>
#include <math.h>

typedef __hip_bfloat16 bf16;
typedef __attribute__((ext_vector_type(8))) short bf16x8v;   // 8 bf16 MFMA operand
typedef __attribute__((ext_vector_type(4))) float f32x4;     // MFMA accumulator

// HGT layer, round 21 = EXACT revert to round 18 (R5 bench: 347.9us, session best).
// R6 lesson: XCD swizzle cut FETCH 193->31MB but slowed gemm3s (not fetch-bound) -> plain.
// R7 lesson: merged ugemm2 (+AGb in ws) cost ~11us (register pressure across two inlined
//   bodies -> 512-thread occupancy boundary) -> separate ugemm_b/ugemm_a restored, AGb
//   back in d_out (Qb3 slot), b FIRST (AGb is where a's output lands).
// EDGE KERNEL AT ROOFLINE (R14-R16): replay(L3-hot)=cold ~109us; ~640MB gather/109us ~=
//   6 TB/s fabric ceiling. gemm3s at its 128^2-structure ceiling (~1 PF effective; R6
//   proved not traffic-bound).
// Dispatches: [zero] [conv||fold6||hist3] [comb5||alloc3b] [gemm3 + scatter-last]
//             [edge] [ugemm_b] [ugemm_a]
// Kept: int2 meta {start,cnt}; int2 CSR lists {src, ML-t}; b-blocks-first edge;
//   shfl_xor(ex,32); VGPR<=64 rule for edge (R15: 72 VGPR = occupancy cliff);
//   scatter-last (R17: scatter-first = whole-GPU atomic phase before gemm, +14us).
//   fold6:    Wq1x/Wq2x/Wq3x = blockdiag(Watt_e*prior/sqrt32)@Wq ; Wmx = blockdiagT(Wmsg)@Wm
//   combine5: RTE-table weights, panel-paired for interleaved outputs
//   gemm3:    seg0 rte->(RKM1,RKM2,RM3p); seg1 Ha->(Qa1,Qa2,KMa1,Ma3); seg2 Hb->(Qb3,KMb)
//   edge:     wave=node, ONE pass/edge-type (softmax by linearity), 4-grouped row loads.
//   ugemm_ln: x=AG@Wa^T -> u=a*x+(1-a)*H_bf -> LN -> fp32 out.
// alloc3b: atomic target must be wave-uniform (R7 lesson: divergent slot = 120k serial atomics).

__device__ __forceinline__ float eluf(float x) { return x > 0.f ? x : (__expf(x) - 1.f); }
__device__ __forceinline__ float b2f(unsigned short u) { return __uint_as_float((unsigned)u << 16); }
__device__ __forceinline__ unsigned short f2b(float f) {
    unsigned u = __float_as_uint(f);
    return (unsigned short)((u + 0x7fffu + ((u >> 16) & 1u)) >> 16);
}
__device__ __forceinline__ void unpack8(uint4 u, float* o) {
    o[0] = __uint_as_float(u.x << 16); o[1] = __uint_as_float(u.x & 0xffff0000u);
    o[2] = __uint_as_float(u.y << 16); o[3] = __uint_as_float(u.y & 0xffff0000u);
    o[4] = __uint_as_float(u.z << 16); o[5] = __uint_as_float(u.z & 0xffff0000u);
    o[6] = __uint_as_float(u.w << 16); o[7] = __uint_as_float(u.w & 0xffff0000u);
}
__device__ __forceinline__ void unpack4(ushort4 u, float* o) {
    o[0] = b2f(u.x); o[1] = b2f(u.y); o[2] = b2f(u.z); o[3] = b2f(u.w);
}

#define ASYNC_LDS16(g, l) \
    __builtin_amdgcn_global_load_lds((const __attribute__((address_space(1))) void*)(g), \
                                     (__attribute__((address_space(3))) void*)(l), 16, 0, 0)

// ---- tiny zero dispatch (must precede hist3's atomics; cannot share its dispatch) ----
__global__ void zero_kernel(int* __restrict__ z0, int nz0, int* __restrict__ z1, int nz1)
{
    for (int i = blockIdx.x * 256 + threadIdx.x; i < nz0; i += gridDim.x * 256) z0[i] = 0;
    if (blockIdx.x == 0 && threadIdx.x < (unsigned)nz1) z1[threadIdx.x] = 0;
}

// ---- merged: 6 fp32->bf16 converts (blocks 0..3071) || fold6 (3072..4607) || hist3 (rest) ----
__global__ void conv_fold_hist_kernel(
    const float* s0, bf16* o0, int n0, const float* s1, bf16* o1, int n1,
    const float* s2, bf16* o2, int n2, const float* s3, bf16* o3, int n3,
    const float* s4, bf16* o4, int n4, const float* s5, bf16* o5, int n5,
    const float* __restrict__ Watt, const float* __restrict__ Wmsg,
    const float* __restrict__ prior,
    const float* __restrict__ Wq, const float* __restrict__ Wm,
    bf16* __restrict__ WcatA, bf16* __restrict__ WcatB,
    float* __restrict__ Wmx1f, float* __restrict__ Wmx2f, float* __restrict__ Wmx3f,
    const int* __restrict__ d1, const int* __restrict__ d2, const int* __restrict__ d3,
    int2* __restrict__ m1, int2* __restrict__ m2, int2* __restrict__ m3,
    int E1, int E2, int E3)
{
    const int bid = blockIdx.x;
    if (bid < 3072) {
        // converts: 512 blocks per segment, grid-stride
        const int seg = bid >> 9;
        const int lb = bid & 511;
        const float* sp; bf16* op; int n8;
        switch (seg) {
            case 0: sp = s0; op = o0; n8 = n0; break;
            case 1: sp = s1; op = o1; n8 = n1; break;
            case 2: sp = s2; op = o2; n8 = n2; break;
            case 3: sp = s3; op = o3; n8 = n3; break;
            case 4: sp = s4; op = o4; n8 = n4; break;
            default: sp = s5; op = o5; n8 = n5; break;
        }
        for (int i = lb * 256 + threadIdx.x; i < n8; i += 512 * 256) {
            const float4* p = (const float4*)(sp + (size_t)i * 8);
            float4 a = p[0], b = p[1];
            uint4 u;
            u.x = (unsigned)f2b(a.x) | ((unsigned)f2b(a.y) << 16);
            u.y = (unsigned)f2b(a.z) | ((unsigned)f2b(a.w) << 16);
            u.z = (unsigned)f2b(b.x) | ((unsigned)f2b(b.y) << 16);
            u.w = (unsigned)f2b(b.z) | ((unsigned)f2b(b.w) << 16);
            *(uint4*)(op + (size_t)i * 8) = u;
        }
        return;
    }
    if (bid >= 4608) {
        // hist3 (last: fills conv's tail). Needs meta zeroed (zero dispatch).
        int i = (bid - 4608) * 256 + threadIdx.x;
        if (i < E1) atomicAdd(&m1[d1[i]].y, 1);
        else if (i < E1 + E2) atomicAdd(&m2[d2[i - E1]].y, 1);
        else if (i < E1 + E2 + E3) atomicAdd(&m3[d3[i - E1 - E2]].y, 1);
        return;
    }
    // fold6
    const int fb = bid - 3072;
    const int g = fb >> 8;
    const int i = fb & 255;
    const int j = threadIdx.x;
    const int h = i >> 5, r = i & 31;
    const float* A; const float* W; float sc = 1.f; int tr = 0;
    bf16* ob; float* of = nullptr;
    const float isq = 0.17677669529663687f;
    switch (g) {
        case 0: A = Watt;        sc = prior[0] * isq; W = Wq;         ob = WcatA;                       break;
        case 1: A = Watt + 1024; sc = prior[1] * isq; W = Wq;         ob = WcatA + (size_t)256 * 256;   break;
        case 2: A = Watt + 2048; sc = prior[2] * isq; W = Wq + 65536; ob = WcatB;                       break;
        case 3: A = Wmsg;        tr = 1; W = Wm;         ob = WcatA + (size_t)768 * 256;  of = Wmx1f;   break;
        case 4: A = Wmsg + 1024; tr = 1; W = Wm + 65536; ob = WcatB + (size_t)512 * 256;  of = Wmx2f;   break;
        default:A = Wmsg + 2048; tr = 1; W = Wm;         ob = WcatA + (size_t)1024 * 256; of = Wmx3f;   break;
    }
    __shared__ float arow[32];
    if (j < 32) arow[j] = (tr ? A[j * 32 + r] : A[r * 32 + j]) * sc;
    __syncthreads();
    float acc = 0.f;
    for (int k = 0; k < 32; ++k) acc += arow[k] * W[(size_t)(h * 32 + k) * 256 + j];
    ((unsigned short*)ob)[(size_t)i * 256 + j] = f2b(acc);
    if (of) of[(size_t)i * 256 + j] = acc;
}

// ---- merged: 5 RTE-weight combines (blocks 0..1279) || alloc3b (rest) ----
__global__ void comb5alloc_kernel(const float* __restrict__ Wk,
                                  const float* __restrict__ Wmx1f, const float* __restrict__ Wmx2f,
                                  const float* __restrict__ Wmx3f,
                                  const float* __restrict__ rteW, const float* __restrict__ rteb,
                                  bf16* __restrict__ WcatR, float* __restrict__ bcatR,
                                  int2* __restrict__ meta, int* __restrict__ cursor,
                                  int* __restrict__ gtot, int NA, int NB, int bps)
{
    if (blockIdx.x >= 1280) {
        // alloc3b: needs meta.y (prev dispatch) + gtot zeroed
        const int lid = (int)blockIdx.x - 1280;
        const int slot = lid / bps;
        const int base = (slot == 0) ? 0 : (slot == 1) ? NA : 2 * NA;
        const int len = (slot == 2) ? NB : NA;
        int i = (lid % bps) * 256 + threadIdx.x;
        if (i >= len) return;
        int* gp = gtot + slot;         // uniform across the block -> wave-reduced atomics
        int idx = base + i;
        int s = atomicAdd(gp, meta[idx].y);
        meta[idx].x = s; cursor[idx] = s;
        return;
    }
    const int g = blockIdx.x >> 8;
    const int i = blockIdx.x & 255;
    const int j = threadIdx.x;
    const float* Wp; const float* rW; const float* rb; int op;
    switch (g) {
        case 0: Wp = Wk;         rW = rteW;         rb = rteb;       op = 0; break;
        case 1: Wp = Wk + 65536; rW = rteW + 65536; rb = rteb + 256; op = 2; break;
        case 2: Wp = Wmx1f;      rW = rteW;         rb = rteb;       op = 1; break;
        case 3: Wp = Wmx2f;      rW = rteW + 65536; rb = rteb + 256; op = 3; break;
        default:Wp = Wmx3f;      rW = rteW;         rb = rteb;       op = 4; break;
    }
    __shared__ float wrow[256];
    wrow[j] = Wp[i * 256 + j];
    __syncthreads();
    float acc = 0.f;
    for (int k = 0; k < 256; ++k) acc += wrow[k] * rW[k * 256 + j];
    ((unsigned short*)WcatR)[(size_t)(op * 256 + i) * 256 + j] = f2b(acc);
    if (j == 0) {
        float b = 0.f;
        for (int k = 0; k < 256; ++k) b += wrow[k] * rb[k];
        bcatR[op * 256 + i] = b;
    }
}

// ---- shared MFMA GEMM body: C{0..4} = A@Wcat^T (+bcat); stride-masked outputs ----
__device__ __forceinline__ void gemm_body(
    const bf16* __restrict__ A, const bf16* __restrict__ Wcat,
    const float* __restrict__ bcat,
    bf16* C0, bf16* C1, bf16* C2, bf16* C3, bf16* C4,
    int wideMask, int M, int bx, int by, char* As, char* Bs)
{
    const int tid = threadIdx.x;
    const int wid = tid >> 6, lane = tid & 63;
    const size_t row0 = (size_t)bx * 128;
    const int gcol0 = by * 128;
    const int cb = by >> 1;
    const int lcol0 = (by & 1) * 128;
    bf16* Csel = (cb == 0) ? C0 : (cb == 1) ? C1 : (cb == 2) ? C2 : (cb == 3) ? C3 : C4;
    const size_t cstride = ((wideMask >> cb) & 1) ? 512 : 256;
    const int wr = wid >> 1, wc = wid & 1;

    f32x4 zero = {0.f, 0.f, 0.f, 0.f};
    f32x4 acc[4][4];
#pragma unroll
    for (int m = 0; m < 4; ++m)
#pragma unroll
        for (int n = 0; n < 4; ++n) acc[m][n] = zero;

    const int sr = wid * 32 + (lane >> 3);
    const int scc = (lane & 7) << 4;
    const char* Ab = (const char*)A;
    const char* Wb = (const char*)Wcat;

    for (int k0 = 0; k0 < 512; k0 += 128) {
#pragma unroll
        for (int i = 0; i < 4; ++i) {
            const int r = sr + i * 8;
            const int csw = scc ^ ((r & 7) << 4);
            const int ldso = wid * 4096 + i * 1024;
            ASYNC_LDS16(Ab + (row0 + r) * 512 + k0 + csw, As + ldso);
            ASYNC_LDS16(Wb + (size_t)(gcol0 + r) * 512 + k0 + csw, Bs + ldso);
        }
        __syncthreads();
#pragma unroll
        for (int kk = 0; kk < 2; ++kk) {
            bf16x8v a[4], b[4];
            const int cbase = kk * 64 + ((lane >> 4) << 4);
#pragma unroll
            for (int m = 0; m < 4; ++m) {
                const int r = wr * 64 + m * 16 + (lane & 15);
                a[m] = *(const bf16x8v*)(As + r * 128 + (cbase ^ ((r & 7) << 4)));
            }
#pragma unroll
            for (int n = 0; n < 4; ++n) {
                const int r = wc * 64 + n * 16 + (lane & 15);
                b[n] = *(const bf16x8v*)(Bs + r * 128 + (cbase ^ ((r & 7) << 4)));
            }
#pragma unroll
            for (int m = 0; m < 4; ++m)
#pragma unroll
                for (int n = 0; n < 4; ++n)
                    acc[m][n] = __builtin_amdgcn_mfma_f32_16x16x32_bf16(a[m], b[n], acc[m][n], 0, 0, 0);
        }
        __syncthreads();
    }
    const int orow = (lane >> 4) << 2;
    const int ocol = lane & 15;
    float bv[4];
#pragma unroll
    for (int n = 0; n < 4; ++n)
        bv[n] = bcat ? bcat[gcol0 + wc * 64 + n * 16 + ocol] : 0.f;
    unsigned short* Cp = (unsigned short*)Csel;
#pragma unroll
    for (int m = 0; m < 4; ++m) {
#pragma unroll
        for (int j = 0; j < 4; ++j) {
            const size_t row = row0 + wr * 64 + m * 16 + orow + j;
            if ((int)row >= M) continue;
#pragma unroll
            for (int n = 0; n < 4; ++n) {
                const int col = lcol0 + wc * 64 + n * 16 + ocol;
                Cp[row * cstride + col] = f2b(acc[m][n][j] + bv[n]);
            }
        }
    }
}

// ---- merged: 3-segment GEMM (plain column-fastest decode) || scatter3 LAST.
// R6 lesson: XCD swizzle cut FETCH 6x but slowed the kernel (not fetch-bound) -> plain.
// Scatter blocks fill the gemm drain tail (R17 lesson: scatter-first serializes).
__global__ __launch_bounds__(256) void gemm3s_kernel(
    const bf16* A0, const bf16* W0, const float* bc0,
    bf16* o00, bf16* o01, bf16* o02, bf16* o03, bf16* o04, int mask0, int M0,
    const bf16* A1, const bf16* W1,
    bf16* o10, bf16* o11, bf16* o12, bf16* o13, bf16* o14, int mask1, int M1,
    const bf16* A2, const bf16* W2,
    bf16* o20, bf16* o21, bf16* o22, int mask2, int M2,
    int b0, int b1, int btot,
    const int* __restrict__ d1, const int* __restrict__ d2, const int* __restrict__ d3,
    const int* __restrict__ s1, const int* __restrict__ s2, const int* __restrict__ s3,
    const int* __restrict__ tv1, const int* __restrict__ tv2, const int* __restrict__ tv3,
    int* __restrict__ cur1, int* __restrict__ cur2, int* __restrict__ cur3,
    int2* __restrict__ el1, int2* __restrict__ el2, int2* __restrict__ el3,
    int E1, int E2, int E3, int ml)
{
    __shared__ __align__(16) char As[16384];
    __shared__ __align__(16) char Bs[16384];
    const int bid = blockIdx.x;
    if (bid >= btot) {
        // scatter3: needs cursors (prev dispatch); completes before edge (dispatch boundary)
        int i = (bid - btot) * 256 + threadIdx.x;
        if (i < E1) {
            int p = atomicAdd(&cur1[d1[i]], 1);
            el1[p] = make_int2(s1[i], ml - tv1[i]);
        } else if (i < E1 + E2) {
            int e = i - E1; int p = atomicAdd(&cur2[d2[e]], 1);
            el2[p] = make_int2(s2[e], ml - tv2[e]);
        } else if (i < E1 + E2 + E3) {
            int e = i - E1 - E2; int p = atomicAdd(&cur3[d3[e]], 1);
            el3[p] = make_int2(s3[e], ml - tv3[e]);
        }
        return;
    }
    if (bid < b0) {
        gemm_body(A0, W0, bc0, o00, o01, o02, o03, o04, mask0, M0,
                  bid / 10, bid % 10, As, Bs);
    } else if (bid < b1) {
        const int lid = bid - b0;
        gemm_body(A1, W1, nullptr, o10, o11, o12, o13, o14, mask1, M1,
                  lid / 10, lid % 10, As, Bs);
    } else {
        const int lid = bid - b1;
        gemm_body(A2, W2, nullptr, o20, o21, o22, o22, o22, mask2, M2,
                  lid / 6, lid % 6, As, Bs);
    }
}

// ---- fused update-GEMM + LayerNorm ----
__global__ __launch_bounds__(512) void ugemm_ln_kernel(
    const bf16* __restrict__ AG, const bf16* __restrict__ Wp,
    const bf16* __restrict__ Hbf, const float* __restrict__ g,
    const float* __restrict__ b, const float* __restrict__ ra,
    float* __restrict__ out, int M)
{
    __shared__ __align__(16) char As[16384];
    __shared__ __align__(16) char Bs[32768];
    __shared__ float red[128][8];
    const int tid = threadIdx.x;
    const int wid = tid >> 6, lane = tid & 63;
    const int wr = wid >> 2, wc = wid & 3;
    const size_t row0 = (size_t)blockIdx.x * 128;

    f32x4 zero = {0.f, 0.f, 0.f, 0.f};
    f32x4 acc[4][4];
#pragma unroll
    for (int m = 0; m < 4; ++m)
#pragma unroll
        for (int n = 0; n < 4; ++n) acc[m][n] = zero;

    const char* Ab = (const char*)AG;
    const char* Wb = (const char*)Wp;
    for (int k0 = 0; k0 < 512; k0 += 128) {
#pragma unroll
        for (int i = 0; i < 2; ++i) {
            const int r = wid * 16 + i * 8 + (lane >> 3);
            const int csw = ((lane & 7) << 4) ^ ((r & 7) << 4);
            ASYNC_LDS16(Ab + (row0 + r) * 512 + k0 + csw, As + (wid * 16 + i * 8) * 128);
        }
#pragma unroll
        for (int i = 0; i < 4; ++i) {
            const int r = wid * 32 + i * 8 + (lane >> 3);
            const int csw = ((lane & 7) << 4) ^ ((r & 7) << 4);
            ASYNC_LDS16(Wb + (size_t)r * 512 + k0 + csw, Bs + (wid * 32 + i * 8) * 128);
        }
        __syncthreads();
#pragma unroll
        for (int kk = 0; kk < 2; ++kk) {
            bf16x8v a[4], bv[4];
            const int cbase = kk * 64 + ((lane >> 4) << 4);
#pragma unroll
            for (int m = 0; m < 4; ++m) {
                const int r = wr * 64 + m * 16 + (lane & 15);
                a[m] = *(const bf16x8v*)(As + r * 128 + (cbase ^ ((r & 7) << 4)));
            }
#pragma unroll
            for (int n = 0; n < 4; ++n) {
                const int r = wc * 64 + n * 16 + (lane & 15);
                bv[n] = *(const bf16x8v*)(Bs + r * 128 + (cbase ^ ((r & 7) << 4)));
            }
#pragma unroll
            for (int m = 0; m < 4; ++m)
#pragma unroll
                for (int n = 0; n < 4; ++n)
                    acc[m][n] = __builtin_amdgcn_mfma_f32_16x16x32_bf16(a[m], bv[n], acc[m][n], 0, 0, 0);
        }
        __syncthreads();
    }
    const float alpha = 1.f / (1.f + __expf(-ra[0]));
    const float beta = 1.f - alpha;
    const int orow = (lane >> 4) << 2;
    const int ocol = lane & 15;
    float gv[4], bb[4];
#pragma unroll
    for (int n = 0; n < 4; ++n) {
        gv[n] = g[wc * 64 + n * 16 + ocol];
        bb[n] = b[wc * 64 + n * 16 + ocol];
    }
    const unsigned short* Hp = (const unsigned short*)Hbf;
#pragma unroll
    for (int m = 0; m < 4; ++m) {
#pragma unroll
        for (int j = 0; j < 4; ++j) {
            const int rl = wr * 64 + m * 16 + orow + j;
            const size_t grow = row0 + rl;
            float s = 0.f, s2 = 0.f;
#pragma unroll
            for (int n = 0; n < 4; ++n) {
                const int col = wc * 64 + n * 16 + ocol;
                float hv = ((int)grow < M) ? b2f(Hp[grow * 256 + col]) : 0.f;
                float u = alpha * acc[m][n][j] + beta * hv;
                acc[m][n][j] = u;
                s += u; s2 += u * u;
            }
            s += __shfl_xor(s, 1); s2 += __shfl_xor(s2, 1);
            s += __shfl_xor(s, 2); s2 += __shfl_xor(s2, 2);
            s += __shfl_xor(s, 4); s2 += __shfl_xor(s2, 4);
            s += __shfl_xor(s, 8); s2 += __shfl_xor(s2, 8);
            if (ocol == 0) { red[rl][wc] = s; red[rl][4 + wc] = s2; }
        }
    }
    __syncthreads();
#pragma unroll
    for (int m = 0; m < 4; ++m) {
#pragma unroll
        for (int j = 0; j < 4; ++j) {
            const int rl = wr * 64 + m * 16 + orow + j;
            const size_t grow = row0 + rl;
            if ((int)grow >= M) continue;
            float S = red[rl][0] + red[rl][1] + red[rl][2] + red[rl][3];
            float S2 = red[rl][4] + red[rl][5] + red[rl][6] + red[rl][7];
            const float mu = S * 0.00390625f;
            const float var = S2 * 0.00390625f - mu * mu;
            const float inv = rsqrtf(var + 1e-5f);
#pragma unroll
            for (int n = 0; n < 4; ++n) {
                const int col = wc * 64 + n * 16 + ocol;
                out[grow * 256 + col] = (acc[m][n][j] - mu) * inv * gv[n] + bb[n];
            }
        }
    }
}

// ---- single-pass edge accumulate, interleaved rows (type-a edge types) ----
// 4-grouped row loads (R14 structure, VGPR-safe).
__device__ __forceinline__ void epass16(
    const bf16* __restrict__ KM, const bf16* __restrict__ RKM,
    const int2* __restrict__ el, int beg, int num,
    int sx_l, int tt_l,                      // preloaded chunk-0 indices (per-lane)
    const float q[8], int lane,
    float s[8], float& denOut)
{
    float den = 0.f;
    const char* KMb = (const char*)KM + lane * 16;
    const char* RMb = (const char*)RKM + lane * 16;
    auto edge = [&](uint4 km, uint4 rm) {
        float a[8], b[8];
        unpack8(km, a); unpack8(rm, b);
#pragma unroll
        for (int x = 0; x < 8; ++x) a[x] += b[x];
        float p = a[0] * q[0] + a[1] * q[1] + a[2] * q[2] + a[3] * q[3]
                + a[4] * q[4] + a[5] * q[5] + a[6] * q[6] + a[7] * q[7];
        p += __shfl_xor(p, 1); p += __shfl_xor(p, 2);
        float ex = __expf(p);
        float exb = __shfl_xor(ex, 32);   // lane 32+i <- lane i's reduced ex (lanes<32: unused)
        den += exb;
#pragma unroll
        for (int x = 0; x < 8; ++x) s[x] += exb * a[x];   // meaningful on M lanes only
    };
    for (int c0 = 0; c0 < num; c0 += 64) {
        int nc = num - c0; if (nc > 64) nc = 64;
        if (c0 > 0) {
            sx_l = 0; tt_l = 0;
            if (lane < nc) { int2 e = el[beg + c0 + lane]; sx_l = e.x; tt_l = e.y; }
        }
        for (int i0 = 0; i0 < nc; i0 += 4) {
            const int rem = nc - i0;
            const int a0 = __shfl(sx_l, i0),     b0 = __shfl(tt_l, i0);
            const int a1 = __shfl(sx_l, i0 | 1), b1 = __shfl(tt_l, i0 | 1);
            const int a2 = __shfl(sx_l, i0 | 2), b2 = __shfl(tt_l, i0 | 2);
            const int a3 = __shfl(sx_l, i0 | 3), b3 = __shfl(tt_l, i0 | 3);
            uint4 km0, rm0, km1, rm1, km2, rm2, km3, rm3;
            km0 = *(const uint4*)(KMb + (size_t)a0 * 1024);
            rm0 = *(const uint4*)(RMb + (size_t)b0 * 1024);
            if (rem > 1) {
                km1 = *(const uint4*)(KMb + (size_t)a1 * 1024);
                rm1 = *(const uint4*)(RMb + (size_t)b1 * 1024);
            }
            if (rem > 2) {
                km2 = *(const uint4*)(KMb + (size_t)a2 * 1024);
                rm2 = *(const uint4*)(RMb + (size_t)b2 * 1024);
            }
            if (rem > 3) {
                km3 = *(const uint4*)(KMb + (size_t)a3 * 1024);
                rm3 = *(const uint4*)(RMb + (size_t)b3 * 1024);
            }
            edge(km0, rm0);
            if (rem > 1) edge(km1, rm1);
            if (rem > 2) edge(km2, rm2);
            if (rem > 3) edge(km3, rm3);
        }
    }
    denOut = den;
}

// ---- single-pass edge accumulate, split rows (e3), 4-grouped ----
__device__ __forceinline__ void epass8(
    const bf16* __restrict__ Kh, const bf16* __restrict__ RKh,   // K halves, stride 512 el
    const bf16* __restrict__ Mt, const bf16* __restrict__ RMt,   // stride 256 el
    const int2* __restrict__ el, int beg, int num,
    int sx_l, int tt_l,
    const float q[4], int lane,
    float s[4], float& denOut)
{
    float den = 0.f;
    const char* Kb = (const char*)Kh + lane * 8;
    const char* Rb = (const char*)RKh + lane * 8;
    const char* Mb = (const char*)Mt + lane * 8;
    const char* Ub = (const char*)RMt + lane * 8;
    auto edge = [&](ushort4 kv, ushort4 rv, ushort4 mv, ushort4 uv) {
        float a[4], b[4], m[4], r[4];
        unpack4(kv, a); unpack4(rv, b); unpack4(mv, m); unpack4(uv, r);
        float p = (a[0] + b[0]) * q[0] + (a[1] + b[1]) * q[1]
                + (a[2] + b[2]) * q[2] + (a[3] + b[3]) * q[3];
        p += __shfl_xor(p, 1); p += __shfl_xor(p, 2); p += __shfl_xor(p, 4);
        float ex = __expf(p);
        den += ex;
#pragma unroll
        for (int x = 0; x < 4; ++x) s[x] += ex * (m[x] + r[x]);
    };
    for (int c0 = 0; c0 < num; c0 += 64) {
        int nc = num - c0; if (nc > 64) nc = 64;
        if (c0 > 0) {
            sx_l = 0; tt_l = 0;
            if (lane < nc) { int2 e = el[beg + c0 + lane]; sx_l = e.x; tt_l = e.y; }
        }
        for (int i0 = 0; i0 < nc; i0 += 4) {
            const int rem = nc - i0;
            const int a0 = __shfl(sx_l, i0),     b0 = __shfl(tt_l, i0);
            const int a1 = __shfl(sx_l, i0 | 1), b1 = __shfl(tt_l, i0 | 1);
            const int a2 = __shfl(sx_l, i0 | 2), b2 = __shfl(tt_l, i0 | 2);
            const int a3 = __shfl(sx_l, i0 | 3), b3 = __shfl(tt_l, i0 | 3);
            ushort4 k0, r0, m0, u0, k1, r1, m1, u1, k2, r2, m2, u2, k3, r3, m3, u3;
            k0 = *(const ushort4*)(Kb + (size_t)a0 * 1024);
            r0 = *(const ushort4*)(Rb + (size_t)b0 * 1024);
            m0 = *(const ushort4*)(Mb + (size_t)a0 * 512);
            u0 = *(const ushort4*)(Ub + (size_t)b0 * 512);
            if (rem > 1) {
                k1 = *(const ushort4*)(Kb + (size_t)a1 * 1024);
                r1 = *(const ushort4*)(Rb + (size_t)b1 * 1024);
                m1 = *(const ushort4*)(Mb + (size_t)a1 * 512);
                u1 = *(const ushort4*)(Ub + (size_t)b1 * 512);
            }
            if (rem > 2) {
                k2 = *(const ushort4*)(Kb + (size_t)a2 * 1024);
                r2 = *(const ushort4*)(Rb + (size_t)b2 * 1024);
                m2 = *(const ushort4*)(Mb + (size_t)a2 * 512);
                u2 = *(const ushort4*)(Ub + (size_t)b2 * 512);
            }
            if (rem > 3) {
                k3 = *(const ushort4*)(Kb + (size_t)a3 * 1024);
                r3 = *(const ushort4*)(Rb + (size_t)b3 * 1024);
                m3 = *(const ushort4*)(Mb + (size_t)a3 * 512);
                u3 = *(const ushort4*)(Ub + (size_t)b3 * 512);
            }
            edge(k0, r0, m0, u0);
            if (rem > 1) edge(k1, r1, m1, u1);
            if (rem > 2) edge(k2, r2, m2, u2);
            if (rem > 3) edge(k3, r3, m3, u3);
        }
    }
    denOut = den;
}

// ---- THE fused edge kernel: blocks [0,nbblk) = type-b (longest waves first), rest type-a ----
__global__ __launch_bounds__(256) void edge_fused_kernel(
    const bf16* __restrict__ Qa1, const bf16* __restrict__ Qa2,
    const bf16* __restrict__ KMa1, const bf16* __restrict__ RKM1,
    const int2* __restrict__ meta1, const int2* __restrict__ el1,
    const bf16* __restrict__ KMb, const bf16* __restrict__ RKM2,
    const int2* __restrict__ meta2, const int2* __restrict__ el2,
    bf16* __restrict__ AGa, int NA,
    const bf16* __restrict__ Qb3, const bf16* __restrict__ Ma3, const bf16* __restrict__ RM3p,
    const int2* __restrict__ meta3, const int2* __restrict__ el3,
    bf16* __restrict__ AGb, int NB, int nbblk)
{
    const int wid = threadIdx.x >> 6, lane = threadIdx.x & 63;
    if ((int)blockIdx.x >= nbblk) {
        const int n = ((int)blockIdx.x - nbblk) * 4 + wid;
        if (n >= NA) return;
        const int2 m1 = meta1[n], m2 = meta2[n];
        const int beg1 = m1.x, num1 = m1.y, beg2 = m2.x, num2 = m2.y;
        // preload chunk-0 indices for BOTH passes (overlaps the el round-trips)
        int sx1 = 0, tt1 = 0, sx2 = 0, tt2 = 0;
        if (lane < (num1 < 64 ? num1 : 64)) { int2 e = el1[beg1 + lane]; sx1 = e.x; tt1 = e.y; }
        if (lane < (num2 < 64 ? num2 : 64)) { int2 e = el2[beg2 + lane]; sx2 = e.x; tt2 = e.y; }
        float q1[8];
        unpack8(*(const uint4*)(Qa1 + (size_t)n * 256 + (lane & 31) * 8), q1);
        const uint4 qv2 = *(const uint4*)(Qa2 + (size_t)n * 256 + (lane & 31) * 8);
        float sf[8] = {0.f, 0.f, 0.f, 0.f, 0.f, 0.f, 0.f, 0.f};
        float s[8], den;
        if (num1 > 0) {
#pragma unroll
            for (int x = 0; x < 8; ++x) s[x] = 0.f;
            epass16(KMa1, RKM1, el1, beg1, num1, sx1, tt1, q1, lane, s, den);
            float invd = 1.f / den;
#pragma unroll
            for (int x = 0; x < 8; ++x) sf[x] += s[x] * invd;
        }
        if (num2 > 0) {
            float q2[8];
            unpack8(qv2, q2);
#pragma unroll
            for (int x = 0; x < 8; ++x) s[x] = 0.f;
            epass16(KMb, RKM2, el2, beg2, num2, sx2, tt2, q2, lane, s, den);
            float invd = 1.f / den;
#pragma unroll
            for (int x = 0; x < 8; ++x) sf[x] += s[x] * invd;
        }
        float dv = 1.f / fmaxf((float)((num1 > 0) + (num2 > 0)), 1.f);
        if (lane >= 32) {
            uint4 o;
            o.x = (unsigned)f2b(eluf(sf[0] * dv)) | ((unsigned)f2b(eluf(sf[1] * dv)) << 16);
            o.y = (unsigned)f2b(eluf(sf[2] * dv)) | ((unsigned)f2b(eluf(sf[3] * dv)) << 16);
            o.z = (unsigned)f2b(eluf(sf[4] * dv)) | ((unsigned)f2b(eluf(sf[5] * dv)) << 16);
            o.w = (unsigned)f2b(eluf(sf[6] * dv)) | ((unsigned)f2b(eluf(sf[7] * dv)) << 16);
            *(uint4*)((unsigned short*)AGa + (size_t)n * 256 + (lane - 32) * 8) = o;
        }
    } else {
        const int n = (int)blockIdx.x * 4 + wid;
        if (n >= NB) return;
        const int2 m3 = meta3[n];
        const int beg3 = m3.x, num3 = m3.y;
        int sx3 = 0, tt3 = 0;
        if (lane < (num3 < 64 ? num3 : 64)) { int2 e = el3[beg3 + lane]; sx3 = e.x; tt3 = e.y; }
        float q3[4];
        unpack4(*(const ushort4*)(Qb3 + (size_t)n * 256 + lane * 4), q3);
        float s[4] = {0.f, 0.f, 0.f, 0.f};
        float den = 1.f;
        if (num3 > 0) {
            epass8(KMa1, RKM1, Ma3, RM3p, el3, beg3, num3, sx3, tt3, q3, lane, s, den);
            float invd = 1.f / den;
#pragma unroll
            for (int x = 0; x < 4; ++x) s[x] *= invd;
        }
        ushort4 o;
        o.x = f2b(eluf(s[0])); o.y = f2b(eluf(s[1]));
        o.z = f2b(eluf(s[2])); o.w = f2b(eluf(s[3]));
        *(ushort4*)((unsigned short*)AGb + (size_t)n * 256 + lane * 4) = o;
    }
}

extern "C" void kernel_launch(void* const* d_in, const int* in_sizes, int n_in,
                              void* d_out, int out_size, void* d_ws, size_t ws_size,
                              hipStream_t stream)
{
    const float* Ha   = (const float*)d_in[0];
    const float* Hb   = (const float*)d_in[1];
    const float* rte  = (const float*)d_in[2];
    const float* Wq   = (const float*)d_in[3];
    const float* Wk   = (const float*)d_in[4];
    const float* Wm   = (const float*)d_in[5];
    const float* Wa   = (const float*)d_in[6];
    const float* rteW = (const float*)d_in[7];
    const float* rteb = (const float*)d_in[8];
    const float* ln_g = (const float*)d_in[9];
    const float* ln_b = (const float*)d_in[10];
    const float* ra   = (const float*)d_in[11];
    const float* Watt = (const float*)d_in[12];
    const float* Wmsg = (const float*)d_in[13];
    const float* prior= (const float*)d_in[14];
    const int* src1 = (const int*)d_in[15];
    const int* dst1 = (const int*)d_in[16];
    const int* t1   = (const int*)d_in[17];
    const int* src2 = (const int*)d_in[18];
    const int* dst2 = (const int*)d_in[19];
    const int* t2   = (const int*)d_in[20];
    const int* src3 = (const int*)d_in[21];
    const int* dst3 = (const int*)d_in[22];
    const int* t3   = (const int*)d_in[23];

    const int NA = in_sizes[0] / 256;
    const int NB = in_sizes[1] / 256;
    const int ML = in_sizes[2] / 256;
    const int E1 = in_sizes[15];
    const int E2 = in_sizes[18];
    const int E3 = in_sizes[21];
    const int NAp = (NA + 127) & ~127;
    const int NBp = (NB + 127) & ~127;
    const int MLp = (ML + 127) & ~127;

    char* w = (char*)d_ws;
    size_t off = 0;
    auto alloc = [&](size_t bytes) -> void* {
        void* p = w + off;
        off += (bytes + 511) & ~(size_t)511;
        return p;
    };
    // weight panels
    bf16* WcatA = (bf16*)alloc((size_t)1280 * 256 * 2);  // [Wq1x|Wq2x|Wk_a|Wmx1|Wmx3]
    bf16* WcatB = (bf16*)alloc((size_t)768 * 256 * 2);   // [Wq3x|Wk_b|Wmx2]
    bf16* WcatR = (bf16*)alloc((size_t)1280 * 256 * 2);  // [Wck0|Wm1'|Wck1|Wm2'|Wm3']
    float* bcatR = (float*)alloc(1280 * 4);
    bf16* Wa_bf = (bf16*)alloc(131072 * 2);
    float* Wmx1f = (float*)alloc(65536 * 4);
    float* Wmx2f = (float*)alloc(65536 * 4);
    float* Wmx3f = (float*)alloc(65536 * 4);
    // bf16 inputs (padded rows)
    bf16* Ha_bf = (bf16*)alloc((size_t)NAp * 512);
    bf16* Hb_bf = (bf16*)alloc((size_t)NBp * 512);
    bf16* rte_bf = (bf16*)alloc((size_t)MLp * 512);
    // projections / tables (ws)
    bf16* Qa1 = (bf16*)alloc((size_t)NAp * 512);     // -> AGa (self-row rewrite)
    bf16* Qa2 = (bf16*)alloc((size_t)NAp * 512);
    bf16* KMa1 = (bf16*)alloc((size_t)NAp * 1024);   // [Ka|Ma1]
    bf16* RKM1 = (bf16*)alloc((size_t)MLp * 1024);   // [RK0|RM1']
    bf16* RKM2 = (bf16*)alloc((size_t)MLp * 1024);   // [RK1|RM2']
    bf16* RM3p = (bf16*)alloc((size_t)MLp * 512);
    // CSR: meta = int2{start,cnt} per node-slot, cursor separate
    int2* meta = (int2*)alloc((size_t)(NA + NA + NB) * 8);
    int2* meta1 = meta, *meta2 = meta + NA, *meta3 = meta + 2 * NA;
    int* curb = (int*)alloc((size_t)(NA + NA + NB) * 4);
    int* cur1 = curb, *cur2 = curb + NA, *cur3 = curb + 2 * NA;
    int2* elist1 = (int2*)alloc((size_t)E1 * 8);
    int2* elist2 = (int2*)alloc((size_t)E2 * 8);
    int2* elist3 = (int2*)alloc((size_t)E3 * 8);
    int* gtot = (int*)alloc(16);
    // d_out scratch: [Ma3 | Qb3 | KMb], all dead before the ugemm_ln writes
    bf16* Ma3 = (bf16*)d_out;
    bf16* Qb3 = (bf16*)d_out + (size_t)NAp * 256;                       // -> AGb
    bf16* KMb = (bf16*)d_out + (size_t)NAp * 256 + (size_t)NBp * 256;   // [Kb|Mb2]
    bf16* AGa = Qa1;
    bf16* AGb = Qb3;

    const int Etot = E1 + E2 + E3;
    const int histB = (Etot + 255) / 256;
    const int bps = (((NA > NB ? NA : NB) + 255) / 256);

    // Dispatch 0: zero meta + gtot (must precede hist3's atomics)
    zero_kernel<<<512, 256, 0, stream>>>((int*)meta, 2 * (NA + NA + NB), gtot, 4);

    // Dispatch 1: converts || fold6 || hist3 (hist last -> fills conv's tail)
    conv_fold_hist_kernel<<<4608 + histB, 256, 0, stream>>>(
        Ha, Ha_bf, NA * 32, Hb, Hb_bf, NB * 32, rte, rte_bf, ML * 32,
        Wa, Wa_bf, 16384,
        Wk, WcatA + (size_t)512 * 256, 8192,
        Wk + 65536, WcatB + (size_t)256 * 256, 8192,
        Watt, Wmsg, prior, Wq, Wm, WcatA, WcatB, Wmx1f, Wmx2f, Wmx3f,
        dst1, dst2, dst3, meta1, meta2, meta3, E1, E2, E3);

    // Dispatch 2: combine5 || alloc3b
    comb5alloc_kernel<<<1280 + bps * 3, 256, 0, stream>>>(
        Wk, Wmx1f, Wmx2f, Wmx3f, rteW, rteb, WcatR, bcatR,
        meta, curb, gtot, NA, NB, bps);

    // Dispatch 3: merged projection GEMMs (plain decode) || scatter3 LAST
    const int nx0 = MLp / 128, nx1 = NAp / 128, nx2 = NBp / 128;
    const int b0 = nx0 * 10;
    const int b1 = b0 + nx1 * 10;
    const int btot = b1 + nx2 * 6;
    gemm3s_kernel<<<dim3(btot + histB), 256, 0, stream>>>(
        rte_bf, WcatR, bcatR, RKM1, RKM1 + 256, RKM2, RKM2 + 256, RM3p, 0xF, ML,
        Ha_bf, WcatA, Qa1, Qa2, KMa1, KMa1 + 256, Ma3, 0xC, NA,
        Hb_bf, WcatB, Qb3, KMb, KMb + 256, 0x6, NB,
        b0, b1, btot,
        dst1, dst2, dst3, src1, src2, src3, t1, t2, t3,
        cur1, cur2, cur3, elist1, elist2, elist3, E1, E2, E3, ML);

    // Dispatch 4: single-pass fused edge kernel (type-b blocks FIRST; AT ROOFLINE, unchanged)
    const int nablk = (NA + 3) / 4;
    const int nbblk = (NB + 3) / 4;
    edge_fused_kernel<<<dim3(nablk + nbblk), 256, 0, stream>>>(
        Qa1, Qa2, KMa1, RKM1, meta1, elist1,
        KMb, RKM2, meta2, elist2,
        AGa, NA,
        Qb3, Ma3, RM3p, meta3, elist3,
        AGb, NB, nbblk);

    // Dispatches 5-6: fused update-GEMM+LN. b FIRST (AGb is in d_out where a's output lands).
    float* out = (float*)d_out;
    ugemm_ln_kernel<<<dim3(NBp / 128), 512, 0, stream>>>(
        AGb, Wa_bf + 65536, Hb_bf, ln_g + 256, ln_b + 256, ra + 1,
        out + (size_t)NA * 256, NB);
    ugemm_ln_kernel<<<dim3(NAp / 128), 512, 0, stream>>>(
        AGa, Wa_bf, Ha_bf, ln_g, ln_b, ra, out, NA);
}